// Round 3
// baseline (4203.077 us; speedup 1.0000x reference)
//
#include <hip/hip_runtime.h>
#include <float.h>

#define NG    32
#define PTS   1024
#define NPTS  (NG*PTS)      // 32768
#define KNN   30
#define DIM   64
#define CHUNK 8192

// ---------------------------------------------------------------------------
// prep: per-point sum of squares (f32 + f64) + transpose XT[f][p]
// ---------------------------------------------------------------------------
template<int F>
__global__ __launch_bounds__(256) void prep_k(const float* __restrict__ X, int ldx,
                                              float* __restrict__ S32,
                                              double* __restrict__ S64,
                                              float* __restrict__ XT) {
    int p = blockIdx.x * 256 + threadIdx.x;
    float s32 = 0.f;
    double s64 = 0.0;
    #pragma unroll
    for (int f = 0; f < F; ++f) {
        float v = X[(size_t)p * ldx + f];
        s32 = fmaf(v, v, s32);
        s64 = fma((double)v, (double)v, s64);
        XT[(size_t)f * NPTS + p] = v;
    }
    S32[p] = s32;
    S64[p] = s64;
}

// per-graph max of S32 (for the prune-margin eps)
__global__ __launch_bounds__(256) void smax_k(const float* __restrict__ S32,
                                              float* __restrict__ SMAX) {
    int g = blockIdx.x;
    int lane = threadIdx.x & 63, wv = threadIdx.x >> 6;
    float m = 0.f;
    for (int t = threadIdx.x; t < PTS; t += 256) m = fmaxf(m, S32[(size_t)g * PTS + t]);
    #pragma unroll
    for (int off = 32; off; off >>= 1) m = fmaxf(m, __shfl_xor(m, off));
    __shared__ float wm[4];
    if (lane == 0) wm[wv] = m;
    __syncthreads();
    if (threadIdx.x == 0)
        SMAX[g] = fmaxf(fmaxf(wm[0], wm[1]), fmaxf(wm[2], wm[3]));
}

// ---------------------------------------------------------------------------
// knn: 1 wave per point. fp32 distances -> binary-search threshold ->
// compact survivors (provable superset of f64 top-30) -> exact f64 rescore
// of <=64 survivors -> in-wave bitonic sort -> write top-30.
// Ordering identical to exact-f64 lax.top_k (lower index on ties).
// ---------------------------------------------------------------------------
template<int F>
__global__ __launch_bounds__(256) void knn_k(const float* __restrict__ X, int ldx,
                                             const float* __restrict__ XT,
                                             const float* __restrict__ S32,
                                             const double* __restrict__ S64,
                                             const float* __restrict__ SMAX,
                                             int* __restrict__ IDX) {
    int wv = threadIdx.x >> 6;
    int lane = threadIdx.x & 63;
    int i = blockIdx.x * 4 + wv;
    int base = i & ~(PTS - 1);
    __shared__ float xis[4][F];
    __shared__ int   surv[4][64];
    __shared__ int   scount[4];
    if (lane < F) xis[wv][lane] = X[(size_t)i * ldx + lane];
    __syncthreads();
    float si = S32[i];
    float smax = SMAX[i >> 10];

    // ---- phase A: fp32 distances, 16 candidates per lane
    float d32[16];
    #pragma unroll
    for (int m = 0; m < 4; ++m) {
        int j0 = (m << 8) + (lane << 2);
        float d0 = 0.f, d1 = 0.f, d2 = 0.f, d3 = 0.f;
        #pragma unroll
        for (int f = 0; f < F; ++f) {
            float xif = xis[wv][f];
            const float4 xj = *reinterpret_cast<const float4*>(&XT[(size_t)f * NPTS + base + j0]);
            d0 = fmaf(xif, xj.x, d0);
            d1 = fmaf(xif, xj.y, d1);
            d2 = fmaf(xif, xj.z, d2);
            d3 = fmaf(xif, xj.w, d3);
        }
        const float4 sj = *reinterpret_cast<const float4*>(&S32[base + j0]);
        d32[m * 4 + 0] = (si + sj.x) - 2.f * d0;
        d32[m * 4 + 1] = (si + sj.y) - 2.f * d1;
        d32[m * 4 + 2] = (si + sj.z) - 2.f * d2;
        d32[m * 4 + 3] = (si + sj.w) - 2.f * d3;
    }

    // ---- threshold: binary search for T with 30 <= count(d32<=T) <= 56
    float lo = -1.f, hi = 2.f * (si + smax) + 1.f;
    for (int it = 0; it < 32; ++it) {
        float piv = 0.5f * (lo + hi);
        int cnt = 0;
        #pragma unroll
        for (int r = 0; r < 16; ++r) cnt += (d32[r] <= piv) ? 1 : 0;
        #pragma unroll
        for (int off = 32; off; off >>= 1) cnt += __shfl_xor(cnt, off);
        if (cnt >= KNN) { hi = piv; if (cnt <= 56) break; }
        else lo = piv;
    }
    // eps: 4x safety over fp32 distance error bound (F+2)*2^-24*(si+sj)
    float T = hi + 1.6e-5f * (si + smax);

    // ---- compact survivors
    if (lane == 0) scount[wv] = 0;
    __syncthreads();
    #pragma unroll
    for (int r = 0; r < 16; ++r) {
        if (d32[r] <= T) {
            int slot = atomicAdd(&scount[wv], 1);
            if (slot < 64) surv[wv][slot] = ((r >> 2) << 8) + (lane << 2) + (r & 3);
        }
    }
    __syncthreads();
    int Ns = scount[wv];

    if (Ns <= 64) {
        // ---- exact f64 rescore of survivors (one per lane)
        double d64 = DBL_MAX;
        int jabs = 0x7fffffff;
        if (lane < Ns) {
            int jl = surv[wv][lane];
            jabs = base + jl;
            const float* xj = X + (size_t)jabs * ldx;
            double dot = 0.0;
            #pragma unroll
            for (int f = 0; f < F; ++f)
                dot = fma((double)xis[wv][f], (double)xj[f], dot);
            d64 = (S64[i] + S64[jabs]) - 2.0 * dot;
        }
        // ---- bitonic sort 64 lanes by (d64, idx) ascending
        #pragma unroll
        for (int k = 2; k <= 64; k <<= 1) {
            #pragma unroll
            for (int s = k >> 1; s > 0; s >>= 1) {
                double od = __shfl_xor(d64, s);
                int oj = __shfl_xor(jabs, s);
                bool otherSmaller = (od < d64) || (od == d64 && oj < jabs);
                bool keepSmaller = (((lane & k) == 0) == ((lane & s) == 0));
                if (otherSmaller == keepSmaller) { d64 = od; jabs = oj; }
            }
        }
        if (lane < KNN) IDX[(size_t)i * KNN + lane] = jabs;
    } else {
        // ---- fallback (never expected): exact f64 on all 1024 + 30x extraction
        double dd[16];
        #pragma unroll
        for (int m = 0; m < 4; ++m) {
            int j0 = (m << 8) + (lane << 2);
            double d0 = 0.0, d1 = 0.0, d2 = 0.0, d3 = 0.0;
            #pragma unroll
            for (int f = 0; f < F; ++f) {
                double xif = (double)xis[wv][f];
                const float4 xj = *reinterpret_cast<const float4*>(&XT[(size_t)f * NPTS + base + j0]);
                d0 = fma(xif, (double)xj.x, d0);
                d1 = fma(xif, (double)xj.y, d1);
                d2 = fma(xif, (double)xj.z, d2);
                d3 = fma(xif, (double)xj.w, d3);
            }
            dd[m * 4 + 0] = (S64[i] + S64[base + j0 + 0]) - 2.0 * d0;
            dd[m * 4 + 1] = (S64[i] + S64[base + j0 + 1]) - 2.0 * d1;
            dd[m * 4 + 2] = (S64[i] + S64[base + j0 + 2]) - 2.0 * d2;
            dd[m * 4 + 3] = (S64[i] + S64[base + j0 + 3]) - 2.0 * d3;
        }
        for (int k = 0; k < KNN; ++k) {
            double bd = DBL_MAX;
            int bj = 0x7fffffff;
            #pragma unroll
            for (int r = 0; r < 16; ++r) {
                int j = ((r >> 2) << 8) + (lane << 2) + (r & 3);
                if (dd[r] < bd) { bd = dd[r]; bj = j; }
            }
            #pragma unroll
            for (int off = 32; off; off >>= 1) {
                double od = __shfl_xor(bd, off);
                int oj = __shfl_xor(bj, off);
                if (od < bd || (od == bd && oj < bj)) { bd = od; bj = oj; }
            }
            if (((bj >> 2) & 63) == lane) {
                int r = ((bj >> 8) << 2) | (bj & 3);
                #pragma unroll
                for (int rr = 0; rr < 16; ++rr) if (rr == r) dd[rr] = DBL_MAX;
            }
            if (lane == 0) IDX[(size_t)i * KNN + k] = base + bj;
        }
    }
}

// ---------------------------------------------------------------------------
// mg: per-point layer-1 decomposition: h1_edge = relu(m_i + g_j)
// ---------------------------------------------------------------------------
template<int F>
__global__ __launch_bounds__(256) void mg_k(const float* __restrict__ X, int ldx,
                                            const float* __restrict__ W1,
                                            const float* __restrict__ B1,
                                            float* __restrict__ Mo, float* __restrict__ Go) {
    int tid = blockIdx.x * 256 + threadIdx.x;
    int pp = tid >> 6, c = tid & 63;
    float m = B1[c], g = 0.f;
    #pragma unroll
    for (int f = 0; f < F; ++f) {
        float xv = X[(size_t)pp * ldx + f];
        float wt = W1[f * DIM + c];
        float wb = W1[(F + f) * DIM + c];
        m = fmaf(xv, wt - wb, m);
        g = fmaf(xv, wb, g);
    }
    Mo[(size_t)pp * DIM + c] = m;
    Go[(size_t)pp * DIM + c] = g;
}

// ---------------------------------------------------------------------------
// edge: per point (1 wave each): h2 = relu(b2 + relu(m_i+g_j) @ W2), max over j.
// h1 buffer is PER-WAVE: intra-wave LDS RAW needs only lgkmcnt drain (DS ops
// complete in order within a wave), not a block barrier.
// ---------------------------------------------------------------------------
__global__ __launch_bounds__(256) void edge_k(const int* __restrict__ IDX,
                                              const float* __restrict__ G,
                                              const float* __restrict__ Mb,
                                              const float* __restrict__ W2,
                                              const float* __restrict__ B2,
                                              float* __restrict__ OUT, int ldo) {
    int wv = threadIdx.x >> 6, lane = threadIdx.x & 63;
    int i = blockIdx.x * 4 + wv;
    __shared__ __align__(16) float h1[4][DIM];
    float w2c[DIM];
    #pragma unroll
    for (int k2 = 0; k2 < DIM; ++k2) w2c[k2] = W2[k2 * DIM + lane];
    float mi = Mb[(size_t)i * DIM + lane];
    float b2c = B2[lane];
    float acc = -FLT_MAX;
    for (int nb = 0; nb < KNN; ++nb) {
        int j = IDX[(size_t)i * KNN + nb];
        float h = fmaxf(mi + G[(size_t)j * DIM + lane], 0.f);
        h1[wv][lane] = h;
        __builtin_amdgcn_wave_barrier();
        asm volatile("s_waitcnt lgkmcnt(0)" ::: "memory");
        float h2 = b2c;
        #pragma unroll
        for (int k2 = 0; k2 < DIM; k2 += 4) {
            const float4 hv = *reinterpret_cast<const float4*>(&h1[wv][k2]);
            h2 = fmaf(hv.x, w2c[k2 + 0], h2);
            h2 = fmaf(hv.y, w2c[k2 + 1], h2);
            h2 = fmaf(hv.z, w2c[k2 + 2], h2);
            h2 = fmaf(hv.w, w2c[k2 + 3], h2);
        }
        acc = fmaxf(acc, fmaxf(h2, 0.f));
        __builtin_amdgcn_wave_barrier();
    }
    OUT[(size_t)i * ldo + lane] = acc;
}

// ---------------------------------------------------------------------------
// fp32 tiled GEMM: C[M x N] = act(A[M x Kd] @ W[Kd x N] + bias)
// ---------------------------------------------------------------------------
template<bool RELU>
__global__ __launch_bounds__(256) void gemm_k(const float* __restrict__ A, int Kd,
                                              const float* __restrict__ W, int N,
                                              const float* __restrict__ Bias,
                                              float* __restrict__ C) {
    __shared__ __align__(16) float As_t[16][68];
    __shared__ __align__(16) float Ws[16][64];
    int bm = blockIdx.y * 64, bn = blockIdx.x * 64;
    int tid = threadIdx.x;
    int tr = tid >> 4, tc = tid & 15;
    float acc[4][4] = {};
    for (int k0 = 0; k0 < Kd; k0 += 16) {
        #pragma unroll
        for (int l = tid; l < 1024; l += 256) {
            int r = l >> 4, cc = l & 15;
            As_t[cc][r] = A[(size_t)(bm + r) * Kd + k0 + cc];
        }
        #pragma unroll
        for (int l = tid; l < 1024; l += 256) {
            int r = l >> 6, cc = l & 63;
            Ws[r][cc] = W[(size_t)(k0 + r) * N + bn + cc];
        }
        __syncthreads();
        #pragma unroll
        for (int kk = 0; kk < 16; ++kk) {
            const float4 av = *reinterpret_cast<const float4*>(&As_t[kk][tr << 2]);
            const float4 wvv = *reinterpret_cast<const float4*>(&Ws[kk][tc << 2]);
            float a4[4] = {av.x, av.y, av.z, av.w};
            float w4[4] = {wvv.x, wvv.y, wvv.z, wvv.w};
            #pragma unroll
            for (int u = 0; u < 4; ++u)
                #pragma unroll
                for (int v = 0; v < 4; ++v)
                    acc[u][v] = fmaf(a4[u], w4[v], acc[u][v]);
        }
        __syncthreads();
    }
    #pragma unroll
    for (int u = 0; u < 4; ++u) {
        int row = bm + (tr << 2) + u;
        float4 o;
        float b0 = Bias[bn + (tc << 2) + 0], b1 = Bias[bn + (tc << 2) + 1];
        float b2 = Bias[bn + (tc << 2) + 2], b3 = Bias[bn + (tc << 2) + 3];
        o.x = acc[u][0] + b0; o.y = acc[u][1] + b1;
        o.z = acc[u][2] + b2; o.w = acc[u][3] + b3;
        if (RELU) {
            o.x = fmaxf(o.x, 0.f); o.y = fmaxf(o.y, 0.f);
            o.z = fmaxf(o.z, 0.f); o.w = fmaxf(o.w, 0.f);
        }
        *reinterpret_cast<float4*>(&C[(size_t)row * N + bn + (tc << 2)]) = o;
    }
}

// ---------------------------------------------------------------------------
template<int F>
static void run_conv(const float* Xin, int ldx,
                     const float* W1, const float* B1,
                     const float* W2, const float* B2,
                     float* OUT, int ldo,
                     float* XT, float* S32, double* S64, float* SMAX,
                     float* Mb, float* Gb, int* IDX,
                     hipStream_t stream) {
    prep_k<F><<<NPTS / 256, 256, 0, stream>>>(Xin, ldx, S32, S64, XT);
    smax_k<<<NG, 256, 0, stream>>>(S32, SMAX);
    knn_k<F><<<NPTS / 4, 256, 0, stream>>>(Xin, ldx, XT, S32, S64, SMAX, IDX);
    mg_k<F><<<NPTS * DIM / 256, 256, 0, stream>>>(Xin, ldx, W1, B1, Mb, Gb);
    edge_k<<<NPTS / 4, 256, 0, stream>>>(IDX, Gb, Mb, W2, B2, OUT, ldo);
}

extern "C" void kernel_launch(void* const* d_in, const int* in_sizes, int n_in,
                              void* d_out, int out_size, void* d_ws, size_t ws_size,
                              hipStream_t stream) {
    (void)in_sizes; (void)n_in; (void)out_size; (void)ws_size;
    const float* x    = (const float*)d_in[0];
    const float* c1w1 = (const float*)d_in[2];  const float* c1b1 = (const float*)d_in[3];
    const float* c1w2 = (const float*)d_in[4];  const float* c1b2 = (const float*)d_in[5];
    const float* c2w1 = (const float*)d_in[6];  const float* c2b1 = (const float*)d_in[7];
    const float* c2w2 = (const float*)d_in[8];  const float* c2b2 = (const float*)d_in[9];
    const float* c3w1 = (const float*)d_in[10]; const float* c3b1 = (const float*)d_in[11];
    const float* c3w2 = (const float*)d_in[12]; const float* c3b2 = (const float*)d_in[13];
    const float* lw   = (const float*)d_in[14]; const float* lb   = (const float*)d_in[15];
    const float* hw1  = (const float*)d_in[16]; const float* hb1  = (const float*)d_in[17];
    const float* hw2  = (const float*)d_in[18]; const float* hb2  = (const float*)d_in[19];
    const float* hw3  = (const float*)d_in[20]; const float* hb3  = (const float*)d_in[21];
    float* out = (float*)d_out;

    // workspace layout: XC | IDX | union(conv scratch, head scratch)
    float* XC  = (float*)d_ws;                       // 32768*192
    int*   IDX = (int*)(XC + (size_t)NPTS * 192);    // 32768*30
    float* SCR = (float*)(IDX + (size_t)NPTS * KNN); // 8B-aligned
    // conv-phase view of SCR
    float*  XT   = SCR;                                   // 64*NPTS floats
    double* S64  = (double*)(XT + (size_t)64 * NPTS);     // NPTS doubles
    float*  S32  = (float*)(S64 + NPTS);                  // NPTS floats
    float*  SMAX = S32 + NPTS;                            // 64 floats (32 used)
    float*  Mb   = SMAX + 64;                             // NPTS*64
    float*  Gb   = Mb + (size_t)NPTS * DIM;               // NPTS*64
    // head-phase view of SCR
    float* H1 = SCR;                        // CHUNK*1024
    float* H2 = H1 + (size_t)CHUNK * 1024;  // CHUNK*256
    float* H3 = H2 + (size_t)CHUNK * 256;   // CHUNK*128

    run_conv<14>(x,        14,  c1w1, c1b1, c1w2, c1b2, XC + 0,   192,
                 XT, S32, S64, SMAX, Mb, Gb, IDX, stream);
    run_conv<64>(XC + 0,   192, c2w1, c2b1, c2w2, c2b2, XC + 64,  192,
                 XT, S32, S64, SMAX, Mb, Gb, IDX, stream);
    run_conv<64>(XC + 64,  192, c3w1, c3b1, c3w2, c3b2, XC + 128, 192,
                 XT, S32, S64, SMAX, Mb, Gb, IDX, stream);

    for (int ch = 0; ch < 4; ++ch) {
        const float* a0 = XC + (size_t)ch * CHUNK * 192;
        float* o0 = out + (size_t)ch * CHUNK * 64;
        gemm_k<true ><<<dim3(1024 / 64, CHUNK / 64), 256, 0, stream>>>(a0, 192,  lw,  1024, lb,  H1);
        gemm_k<true ><<<dim3(256  / 64, CHUNK / 64), 256, 0, stream>>>(H1, 1024, hw1, 256,  hb1, H2);
        gemm_k<true ><<<dim3(128  / 64, CHUNK / 64), 256, 0, stream>>>(H2, 256,  hw2, 128,  hb2, H3);
        gemm_k<false><<<dim3(64   / 64, CHUNK / 64), 256, 0, stream>>>(H3, 128,  hw3, 64,   hb3, o0);
    }
}

// Round 4
// 2349.340 us; speedup vs baseline: 1.7890x; 1.7890x over previous
//
#include <hip/hip_runtime.h>
#include <float.h>

#define NG    32
#define PTS   1024
#define NPTS  (NG*PTS)      // 32768
#define KNN   30
#define DIM   64
#define CHUNK 8192

// ---------------------------------------------------------------------------
// prep: per-point sum of squares (f32 + f64) + transpose XT[f][p]
// ---------------------------------------------------------------------------
template<int F>
__global__ __launch_bounds__(256) void prep_k(const float* __restrict__ X, int ldx,
                                              float* __restrict__ S32,
                                              double* __restrict__ S64,
                                              float* __restrict__ XT) {
    int p = blockIdx.x * 256 + threadIdx.x;
    float s32 = 0.f;
    double s64 = 0.0;
    #pragma unroll
    for (int f = 0; f < F; ++f) {
        float v = X[(size_t)p * ldx + f];
        s32 = fmaf(v, v, s32);
        s64 = fma((double)v, (double)v, s64);
        XT[(size_t)f * NPTS + p] = v;
    }
    S32[p] = s32;
    S64[p] = s64;
}

// per-graph max of S32 (for the prune-margin eps) + zero the overflow counter
__global__ __launch_bounds__(256) void smax_k(const float* __restrict__ S32,
                                              float* __restrict__ SMAX,
                                              int* __restrict__ ovf_cnt) {
    if (blockIdx.x == 0 && threadIdx.x == 0) *ovf_cnt = 0;
    int g = blockIdx.x;
    int lane = threadIdx.x & 63, wv = threadIdx.x >> 6;
    float m = 0.f;
    for (int t = threadIdx.x; t < PTS; t += 256) m = fmaxf(m, S32[(size_t)g * PTS + t]);
    #pragma unroll
    for (int off = 32; off; off >>= 1) m = fmaxf(m, __shfl_xor(m, off));
    __shared__ float wm[4];
    if (lane == 0) wm[wv] = m;
    __syncthreads();
    if (threadIdx.x == 0)
        SMAX[g] = fmaxf(fmaxf(wm[0], wm[1]), fmaxf(wm[2], wm[3]));
}

// ---------------------------------------------------------------------------
// knn (hot path only): fp32 distances -> binary-search threshold -> compact
// survivors (provable superset of the f64 top-30) -> exact f64 rescore of
// <=64 survivors -> in-wave bitonic sort -> write top-30.
// Overflow (>64 survivors, ~never) is deferred to fb_k to keep VGPRs low.
// ---------------------------------------------------------------------------
template<int F>
__global__ __launch_bounds__(256) void knn_k(const float* __restrict__ X, int ldx,
                                             const float* __restrict__ XT,
                                             const float* __restrict__ S32,
                                             const double* __restrict__ S64,
                                             const float* __restrict__ SMAX,
                                             int* __restrict__ IDX,
                                             int* __restrict__ ovf_cnt,
                                             int* __restrict__ ovf_list) {
    int wv = threadIdx.x >> 6;
    int lane = threadIdx.x & 63;
    int i = blockIdx.x * 4 + wv;
    int base = i & ~(PTS - 1);
    __shared__ float xis[4][F];
    __shared__ int   surv[4][64];
    __shared__ int   scount[4];
    if (lane < F) xis[wv][lane] = X[(size_t)i * ldx + lane];
    __syncthreads();
    float si = S32[i];
    float smax = SMAX[i >> 10];

    // ---- phase A: fp32 distances, 16 candidates per lane
    float d32[16];
    #pragma unroll
    for (int m = 0; m < 4; ++m) {
        int j0 = (m << 8) + (lane << 2);
        float d0 = 0.f, d1 = 0.f, d2 = 0.f, d3 = 0.f;
        #pragma unroll
        for (int f = 0; f < F; ++f) {
            float xif = xis[wv][f];
            const float4 xj = *reinterpret_cast<const float4*>(&XT[(size_t)f * NPTS + base + j0]);
            d0 = fmaf(xif, xj.x, d0);
            d1 = fmaf(xif, xj.y, d1);
            d2 = fmaf(xif, xj.z, d2);
            d3 = fmaf(xif, xj.w, d3);
        }
        const float4 sj = *reinterpret_cast<const float4*>(&S32[base + j0]);
        d32[m * 4 + 0] = (si + sj.x) - 2.f * d0;
        d32[m * 4 + 1] = (si + sj.y) - 2.f * d1;
        d32[m * 4 + 2] = (si + sj.z) - 2.f * d2;
        d32[m * 4 + 3] = (si + sj.w) - 2.f * d3;
    }

    // ---- threshold: binary search for T with 30 <= count(d32<=T) <= 56
    float lo = -1.f, hi = 2.f * (si + smax) + 1.f;
    for (int it = 0; it < 32; ++it) {
        float piv = 0.5f * (lo + hi);
        int cnt = 0;
        #pragma unroll
        for (int r = 0; r < 16; ++r) cnt += (d32[r] <= piv) ? 1 : 0;
        #pragma unroll
        for (int off = 32; off; off >>= 1) cnt += __shfl_xor(cnt, off);
        if (cnt >= KNN) { hi = piv; if (cnt <= 56) break; }
        else lo = piv;
    }
    // eps: 4x safety over fp32 distance error bound (F+2)*2^-24*(si+sj)
    float T = hi + 1.6e-5f * (si + smax);

    // ---- compact survivors
    if (lane == 0) scount[wv] = 0;
    __builtin_amdgcn_wave_barrier();
    asm volatile("s_waitcnt lgkmcnt(0)" ::: "memory");
    #pragma unroll
    for (int r = 0; r < 16; ++r) {
        if (d32[r] <= T) {
            int slot = atomicAdd(&scount[wv], 1);
            if (slot < 64) surv[wv][slot] = ((r >> 2) << 8) + (lane << 2) + (r & 3);
        }
    }
    __builtin_amdgcn_wave_barrier();
    asm volatile("s_waitcnt lgkmcnt(0)" ::: "memory");
    int Ns = scount[wv];

    if (Ns > 64) {                      // ~never: defer to fb_k
        if (lane == 0) ovf_list[atomicAdd(ovf_cnt, 1)] = i;
        return;
    }

    // ---- exact f64 rescore of survivors (one per lane)
    double d64 = DBL_MAX;
    int jabs = 0x7fffffff;
    if (lane < Ns) {
        int jl = surv[wv][lane];
        jabs = base + jl;
        double dot = 0.0;
        if constexpr ((F & 3) == 0) {
            const float4* xj4 = reinterpret_cast<const float4*>(X + (size_t)jabs * ldx);
            #pragma unroll
            for (int f4 = 0; f4 < F / 4; ++f4) {
                float4 xv = xj4[f4];
                dot = fma((double)xis[wv][f4 * 4 + 0], (double)xv.x, dot);
                dot = fma((double)xis[wv][f4 * 4 + 1], (double)xv.y, dot);
                dot = fma((double)xis[wv][f4 * 4 + 2], (double)xv.z, dot);
                dot = fma((double)xis[wv][f4 * 4 + 3], (double)xv.w, dot);
            }
        } else {
            const float* xj = X + (size_t)jabs * ldx;
            #pragma unroll
            for (int f = 0; f < F; ++f)
                dot = fma((double)xis[wv][f], (double)xj[f], dot);
        }
        d64 = (S64[i] + S64[jabs]) - 2.0 * dot;
    }
    // ---- bitonic sort 64 lanes by (d64, idx) ascending
    #pragma unroll
    for (int k = 2; k <= 64; k <<= 1) {
        #pragma unroll
        for (int s = k >> 1; s > 0; s >>= 1) {
            double od = __shfl_xor(d64, s);
            int oj = __shfl_xor(jabs, s);
            bool otherSmaller = (od < d64) || (od == d64 && oj < jabs);
            bool keepSmaller = (((lane & k) == 0) == ((lane & s) == 0));
            if (otherSmaller == keepSmaller) { d64 = od; jabs = oj; }
        }
    }
    if (lane < KNN) IDX[(size_t)i * KNN + lane] = jabs;
}

// ---------------------------------------------------------------------------
// fb_k: exact f64 full scan + 30x min-extract for overflow points only.
// Fixed grid (graph-safe); normally zero work. Register pressure isolated here.
// ---------------------------------------------------------------------------
template<int F>
__global__ __launch_bounds__(256) void fb_k(const float* __restrict__ X, int ldx,
                                            const float* __restrict__ XT,
                                            const double* __restrict__ S64,
                                            int* __restrict__ IDX,
                                            const int* __restrict__ ovf_cnt,
                                            const int* __restrict__ ovf_list) {
    int wv = threadIdx.x >> 6, lane = threadIdx.x & 63;
    int novf = *ovf_cnt;
    __shared__ double xis[4][F];
    for (int t = blockIdx.x * 4 + wv; t < novf; t += 64 * 4) {
        int i = ovf_list[t];
        int base = i & ~(PTS - 1);
        if (lane < F) xis[wv][lane] = (double)X[(size_t)i * ldx + lane];
        __builtin_amdgcn_wave_barrier();
        asm volatile("s_waitcnt lgkmcnt(0)" ::: "memory");
        double dd[16];
        #pragma unroll
        for (int m = 0; m < 4; ++m) {
            int j0 = (m << 8) + (lane << 2);
            double d0 = 0.0, d1 = 0.0, d2 = 0.0, d3 = 0.0;
            #pragma unroll
            for (int f = 0; f < F; ++f) {
                double xif = xis[wv][f];
                const float4 xj = *reinterpret_cast<const float4*>(&XT[(size_t)f * NPTS + base + j0]);
                d0 = fma(xif, (double)xj.x, d0);
                d1 = fma(xif, (double)xj.y, d1);
                d2 = fma(xif, (double)xj.z, d2);
                d3 = fma(xif, (double)xj.w, d3);
            }
            dd[m * 4 + 0] = (S64[i] + S64[base + j0 + 0]) - 2.0 * d0;
            dd[m * 4 + 1] = (S64[i] + S64[base + j0 + 1]) - 2.0 * d1;
            dd[m * 4 + 2] = (S64[i] + S64[base + j0 + 2]) - 2.0 * d2;
            dd[m * 4 + 3] = (S64[i] + S64[base + j0 + 3]) - 2.0 * d3;
        }
        for (int k = 0; k < KNN; ++k) {
            double bd = DBL_MAX;
            int bj = 0x7fffffff;
            #pragma unroll
            for (int r = 0; r < 16; ++r) {
                int j = ((r >> 2) << 8) + (lane << 2) + (r & 3);
                if (dd[r] < bd) { bd = dd[r]; bj = j; }
            }
            #pragma unroll
            for (int off = 32; off; off >>= 1) {
                double od = __shfl_xor(bd, off);
                int oj = __shfl_xor(bj, off);
                if (od < bd || (od == bd && oj < bj)) { bd = od; bj = oj; }
            }
            if (((bj >> 2) & 63) == lane) {
                int r = ((bj >> 8) << 2) | (bj & 3);
                #pragma unroll
                for (int rr = 0; rr < 16; ++rr) if (rr == r) dd[rr] = DBL_MAX;
            }
            if (lane == 0) IDX[(size_t)i * KNN + k] = base + bj;
        }
        __builtin_amdgcn_wave_barrier();
    }
}

// ---------------------------------------------------------------------------
// mg: per-point layer-1 decomposition: h1_edge = relu(m_i + g_j)
// ---------------------------------------------------------------------------
template<int F>
__global__ __launch_bounds__(256) void mg_k(const float* __restrict__ X, int ldx,
                                            const float* __restrict__ W1,
                                            const float* __restrict__ B1,
                                            float* __restrict__ Mo, float* __restrict__ Go) {
    int tid = blockIdx.x * 256 + threadIdx.x;
    int pp = tid >> 6, c = tid & 63;
    float m = B1[c], g = 0.f;
    #pragma unroll
    for (int f = 0; f < F; ++f) {
        float xv = X[(size_t)pp * ldx + f];
        float wt = W1[f * DIM + c];
        float wb = W1[(F + f) * DIM + c];
        m = fmaf(xv, wt - wb, m);
        g = fmaf(xv, wb, g);
    }
    Mo[(size_t)pp * DIM + c] = m;
    Go[(size_t)pp * DIM + c] = g;
}

// ---------------------------------------------------------------------------
// edge: per point (1 wave each): h2 = relu(b2 + relu(m_i+g_j) @ W2), max over j.
// Per-wave LDS buffer: intra-wave RAW needs only lgkmcnt drain, no barrier.
// ---------------------------------------------------------------------------
__global__ __launch_bounds__(256) void edge_k(const int* __restrict__ IDX,
                                              const float* __restrict__ G,
                                              const float* __restrict__ Mb,
                                              const float* __restrict__ W2,
                                              const float* __restrict__ B2,
                                              float* __restrict__ OUT, int ldo) {
    int wv = threadIdx.x >> 6, lane = threadIdx.x & 63;
    int i = blockIdx.x * 4 + wv;
    __shared__ __align__(16) float h1[4][DIM];
    float w2c[DIM];
    #pragma unroll
    for (int k2 = 0; k2 < DIM; ++k2) w2c[k2] = W2[k2 * DIM + lane];
    float mi = Mb[(size_t)i * DIM + lane];
    float b2c = B2[lane];
    float acc = -FLT_MAX;
    for (int nb = 0; nb < KNN; ++nb) {
        int j = IDX[(size_t)i * KNN + nb];
        float h = fmaxf(mi + G[(size_t)j * DIM + lane], 0.f);
        h1[wv][lane] = h;
        __builtin_amdgcn_wave_barrier();
        asm volatile("s_waitcnt lgkmcnt(0)" ::: "memory");
        float h2 = b2c;
        #pragma unroll
        for (int k2 = 0; k2 < DIM; k2 += 4) {
            const float4 hv = *reinterpret_cast<const float4*>(&h1[wv][k2]);
            h2 = fmaf(hv.x, w2c[k2 + 0], h2);
            h2 = fmaf(hv.y, w2c[k2 + 1], h2);
            h2 = fmaf(hv.z, w2c[k2 + 2], h2);
            h2 = fmaf(hv.w, w2c[k2 + 3], h2);
        }
        acc = fmaxf(acc, fmaxf(h2, 0.f));
        __builtin_amdgcn_wave_barrier();
    }
    OUT[(size_t)i * ldo + lane] = acc;
}

// ---------------------------------------------------------------------------
// fp32 tiled GEMM: C[M x N] = act(A[M x Kd] @ W[Kd x N] + bias)
// ---------------------------------------------------------------------------
template<bool RELU>
__global__ __launch_bounds__(256) void gemm_k(const float* __restrict__ A, int Kd,
                                              const float* __restrict__ W, int N,
                                              const float* __restrict__ Bias,
                                              float* __restrict__ C) {
    __shared__ __align__(16) float As_t[16][68];
    __shared__ __align__(16) float Ws[16][64];
    int bm = blockIdx.y * 64, bn = blockIdx.x * 64;
    int tid = threadIdx.x;
    int tr = tid >> 4, tc = tid & 15;
    float acc[4][4] = {};
    for (int k0 = 0; k0 < Kd; k0 += 16) {
        #pragma unroll
        for (int l = tid; l < 1024; l += 256) {
            int r = l >> 4, cc = l & 15;
            As_t[cc][r] = A[(size_t)(bm + r) * Kd + k0 + cc];
        }
        #pragma unroll
        for (int l = tid; l < 1024; l += 256) {
            int r = l >> 6, cc = l & 63;
            Ws[r][cc] = W[(size_t)(k0 + r) * N + bn + cc];
        }
        __syncthreads();
        #pragma unroll
        for (int kk = 0; kk < 16; ++kk) {
            const float4 av = *reinterpret_cast<const float4*>(&As_t[kk][tr << 2]);
            const float4 wvv = *reinterpret_cast<const float4*>(&Ws[kk][tc << 2]);
            float a4[4] = {av.x, av.y, av.z, av.w};
            float w4[4] = {wvv.x, wvv.y, wvv.z, wvv.w};
            #pragma unroll
            for (int u = 0; u < 4; ++u)
                #pragma unroll
                for (int v = 0; v < 4; ++v)
                    acc[u][v] = fmaf(a4[u], w4[v], acc[u][v]);
        }
        __syncthreads();
    }
    #pragma unroll
    for (int u = 0; u < 4; ++u) {
        int row = bm + (tr << 2) + u;
        float4 o;
        float b0 = Bias[bn + (tc << 2) + 0], b1 = Bias[bn + (tc << 2) + 1];
        float b2 = Bias[bn + (tc << 2) + 2], b3 = Bias[bn + (tc << 2) + 3];
        o.x = acc[u][0] + b0; o.y = acc[u][1] + b1;
        o.z = acc[u][2] + b2; o.w = acc[u][3] + b3;
        if (RELU) {
            o.x = fmaxf(o.x, 0.f); o.y = fmaxf(o.y, 0.f);
            o.z = fmaxf(o.z, 0.f); o.w = fmaxf(o.w, 0.f);
        }
        *reinterpret_cast<float4*>(&C[(size_t)row * N + bn + (tc << 2)]) = o;
    }
}

// ---------------------------------------------------------------------------
template<int F>
static void run_conv(const float* Xin, int ldx,
                     const float* W1, const float* B1,
                     const float* W2, const float* B2,
                     float* OUT, int ldo,
                     float* XT, float* S32, double* S64, float* SMAX,
                     float* Mb, float* Gb, int* IDX,
                     int* ovf_cnt, int* ovf_list,
                     hipStream_t stream) {
    prep_k<F><<<NPTS / 256, 256, 0, stream>>>(Xin, ldx, S32, S64, XT);
    smax_k<<<NG, 256, 0, stream>>>(S32, SMAX, ovf_cnt);
    knn_k<F><<<NPTS / 4, 256, 0, stream>>>(Xin, ldx, XT, S32, S64, SMAX, IDX,
                                           ovf_cnt, ovf_list);
    fb_k<F><<<64, 256, 0, stream>>>(Xin, ldx, XT, S64, IDX, ovf_cnt, ovf_list);
    mg_k<F><<<NPTS * DIM / 256, 256, 0, stream>>>(Xin, ldx, W1, B1, Mb, Gb);
    edge_k<<<NPTS / 4, 256, 0, stream>>>(IDX, Gb, Mb, W2, B2, OUT, ldo);
}

extern "C" void kernel_launch(void* const* d_in, const int* in_sizes, int n_in,
                              void* d_out, int out_size, void* d_ws, size_t ws_size,
                              hipStream_t stream) {
    (void)in_sizes; (void)n_in; (void)out_size; (void)ws_size;
    const float* x    = (const float*)d_in[0];
    const float* c1w1 = (const float*)d_in[2];  const float* c1b1 = (const float*)d_in[3];
    const float* c1w2 = (const float*)d_in[4];  const float* c1b2 = (const float*)d_in[5];
    const float* c2w1 = (const float*)d_in[6];  const float* c2b1 = (const float*)d_in[7];
    const float* c2w2 = (const float*)d_in[8];  const float* c2b2 = (const float*)d_in[9];
    const float* c3w1 = (const float*)d_in[10]; const float* c3b1 = (const float*)d_in[11];
    const float* c3w2 = (const float*)d_in[12]; const float* c3b2 = (const float*)d_in[13];
    const float* lw   = (const float*)d_in[14]; const float* lb   = (const float*)d_in[15];
    const float* hw1  = (const float*)d_in[16]; const float* hb1  = (const float*)d_in[17];
    const float* hw2  = (const float*)d_in[18]; const float* hb2  = (const float*)d_in[19];
    const float* hw3  = (const float*)d_in[20]; const float* hb3  = (const float*)d_in[21];
    float* out = (float*)d_out;

    // workspace layout: XC | IDX | OVF | union(conv scratch, head scratch)
    float* XC  = (float*)d_ws;                        // NPTS*192
    int*   IDX = (int*)(XC + (size_t)NPTS * 192);     // NPTS*30
    int*   ovf_cnt  = IDX + (size_t)NPTS * KNN;       // 1
    int*   ovf_list = ovf_cnt + 1;                    // NPTS
    float* SCR = (float*)(ovf_list + NPTS + 1);       // even offset -> 8B aligned
    // conv-phase view of SCR
    float*  XT   = SCR;                                   // 64*NPTS floats
    double* S64  = (double*)(XT + (size_t)64 * NPTS);     // NPTS doubles
    float*  S32  = (float*)(S64 + NPTS);                  // NPTS floats
    float*  SMAX = S32 + NPTS;                            // 64 floats (32 used)
    float*  Mb   = SMAX + 64;                             // NPTS*64
    float*  Gb   = Mb + (size_t)NPTS * DIM;               // NPTS*64
    // head-phase view of SCR
    float* H1 = SCR;                        // CHUNK*1024
    float* H2 = H1 + (size_t)CHUNK * 1024;  // CHUNK*256
    float* H3 = H2 + (size_t)CHUNK * 256;   // CHUNK*128

    run_conv<14>(x,        14,  c1w1, c1b1, c1w2, c1b2, XC + 0,   192,
                 XT, S32, S64, SMAX, Mb, Gb, IDX, ovf_cnt, ovf_list, stream);
    run_conv<64>(XC + 0,   192, c2w1, c2b1, c2w2, c2b2, XC + 64,  192,
                 XT, S32, S64, SMAX, Mb, Gb, IDX, ovf_cnt, ovf_list, stream);
    run_conv<64>(XC + 64,  192, c3w1, c3b1, c3w2, c3b2, XC + 128, 192,
                 XT, S32, S64, SMAX, Mb, Gb, IDX, ovf_cnt, ovf_list, stream);

    for (int ch = 0; ch < 4; ++ch) {
        const float* a0 = XC + (size_t)ch * CHUNK * 192;
        float* o0 = out + (size_t)ch * CHUNK * 64;
        gemm_k<true ><<<dim3(1024 / 64, CHUNK / 64), 256, 0, stream>>>(a0, 192,  lw,  1024, lb,  H1);
        gemm_k<true ><<<dim3(256  / 64, CHUNK / 64), 256, 0, stream>>>(H1, 1024, hw1, 256,  hb1, H2);
        gemm_k<true ><<<dim3(128  / 64, CHUNK / 64), 256, 0, stream>>>(H2, 256,  hw2, 128,  hb2, H3);
        gemm_k<false><<<dim3(64   / 64, CHUNK / 64), 256, 0, stream>>>(H3, 128,  hw3, 64,   hb3, o0);
    }
}

// Round 5
// 1923.778 us; speedup vs baseline: 2.1848x; 1.2212x over previous
//
#include <hip/hip_runtime.h>
#include <float.h>

#define NG    32
#define PTS   1024
#define NPTS  (NG*PTS)      // 32768
#define KNN   30
#define DIM   64
#define CHUNK 8192

// ---------------------------------------------------------------------------
// prep: per-point sum of squares (f32 + f64) + transpose XT[f][p]
// ---------------------------------------------------------------------------
template<int F>
__global__ __launch_bounds__(256) void prep_k(const float* __restrict__ X, int ldx,
                                              float* __restrict__ S32,
                                              double* __restrict__ S64,
                                              float* __restrict__ XT) {
    int p = blockIdx.x * 256 + threadIdx.x;
    float s32 = 0.f;
    double s64 = 0.0;
    #pragma unroll
    for (int f = 0; f < F; ++f) {
        float v = X[(size_t)p * ldx + f];
        s32 = fmaf(v, v, s32);
        s64 = fma((double)v, (double)v, s64);
        XT[(size_t)f * NPTS + p] = v;
    }
    S32[p] = s32;
    S64[p] = s64;
}

// per-graph max of S32 (for the prune-margin eps) + zero the overflow counter
__global__ __launch_bounds__(256) void smax_k(const float* __restrict__ S32,
                                              float* __restrict__ SMAX,
                                              int* __restrict__ ovf_cnt) {
    if (blockIdx.x == 0 && threadIdx.x == 0) *ovf_cnt = 0;
    int g = blockIdx.x;
    int lane = threadIdx.x & 63, wv = threadIdx.x >> 6;
    float m = 0.f;
    for (int t = threadIdx.x; t < PTS; t += 256) m = fmaxf(m, S32[(size_t)g * PTS + t]);
    #pragma unroll
    for (int off = 32; off; off >>= 1) m = fmaxf(m, __shfl_xor(m, off));
    __shared__ float wm[4];
    if (lane == 0) wm[wv] = m;
    __syncthreads();
    if (threadIdx.x == 0)
        SMAX[g] = fmaxf(fmaxf(wm[0], wm[1]), fmaxf(wm[2], wm[3]));
}

// ---------------------------------------------------------------------------
// knn: block = 16 points, each wave owns 4 points (4x data reuse per load).
// fp32 distances -> ballot-bisection threshold -> ballot-prefix compact ->
// exact f64 rescore of <=64 survivors -> in-wave bitonic -> top-30.
// Overflow (>64 survivors, ~never) deferred to fb_k.
// ---------------------------------------------------------------------------
template<int F>
__global__ __launch_bounds__(256) void knn_k(const float* __restrict__ X, int ldx,
                                             const float* __restrict__ XT,
                                             const float* __restrict__ S32,
                                             const double* __restrict__ S64,
                                             const float* __restrict__ SMAX,
                                             int* __restrict__ IDX,
                                             int* __restrict__ ovf_cnt,
                                             int* __restrict__ ovf_list) {
    constexpr int FP = (F + 3) & ~3;          // padded row for float4 LDS reads
    int wv = threadIdx.x >> 6;
    int lane = threadIdx.x & 63;
    int i0 = blockIdx.x * 16;                 // 16 points per block, one graph
    int base = i0 & ~(PTS - 1);
    __shared__ __align__(16) float xis[16][FP];
    __shared__ int surv[4][4][64];
    for (int l = threadIdx.x; l < 16 * F; l += 256) {
        int pt = l / F, f = l - pt * F;
        xis[pt][f] = X[(size_t)(i0 + pt) * ldx + f];
    }
    __syncthreads();

    float si[4];
    #pragma unroll
    for (int ii = 0; ii < 4; ++ii) si[ii] = S32[i0 + wv * 4 + ii];
    float smax = SMAX[i0 >> 10];

    // ---- phase A: fp32 dot products, 16 j per lane x 4 i per wave
    float d32[4][16];
    #pragma unroll
    for (int ii = 0; ii < 4; ++ii)
        #pragma unroll
        for (int r = 0; r < 16; ++r) d32[ii][r] = 0.f;

    constexpr int F4 = F & ~3;
    for (int f4 = 0; f4 < F4; f4 += 4) {
        float4 xi[4];
        #pragma unroll
        for (int ii = 0; ii < 4; ++ii)
            xi[ii] = *reinterpret_cast<const float4*>(&xis[wv * 4 + ii][f4]);
        #pragma unroll
        for (int fo = 0; fo < 4; ++fo) {
            int f = f4 + fo;
            #pragma unroll
            for (int m = 0; m < 4; ++m) {
                const float4 xj = *reinterpret_cast<const float4*>(
                    &XT[(size_t)f * NPTS + base + (m << 8) + (lane << 2)]);
                #pragma unroll
                for (int ii = 0; ii < 4; ++ii) {
                    float xif = (fo == 0) ? xi[ii].x : (fo == 1) ? xi[ii].y
                               : (fo == 2) ? xi[ii].z : xi[ii].w;
                    d32[ii][m * 4 + 0] = fmaf(xif, xj.x, d32[ii][m * 4 + 0]);
                    d32[ii][m * 4 + 1] = fmaf(xif, xj.y, d32[ii][m * 4 + 1]);
                    d32[ii][m * 4 + 2] = fmaf(xif, xj.z, d32[ii][m * 4 + 2]);
                    d32[ii][m * 4 + 3] = fmaf(xif, xj.w, d32[ii][m * 4 + 3]);
                }
            }
        }
    }
    for (int f = F4; f < F; ++f) {          // tail (F=14)
        float xif[4];
        #pragma unroll
        for (int ii = 0; ii < 4; ++ii) xif[ii] = xis[wv * 4 + ii][f];
        #pragma unroll
        for (int m = 0; m < 4; ++m) {
            const float4 xj = *reinterpret_cast<const float4*>(
                &XT[(size_t)f * NPTS + base + (m << 8) + (lane << 2)]);
            #pragma unroll
            for (int ii = 0; ii < 4; ++ii) {
                d32[ii][m * 4 + 0] = fmaf(xif[ii], xj.x, d32[ii][m * 4 + 0]);
                d32[ii][m * 4 + 1] = fmaf(xif[ii], xj.y, d32[ii][m * 4 + 1]);
                d32[ii][m * 4 + 2] = fmaf(xif[ii], xj.z, d32[ii][m * 4 + 2]);
                d32[ii][m * 4 + 3] = fmaf(xif[ii], xj.w, d32[ii][m * 4 + 3]);
            }
        }
    }
    // finalize d = si + sj - 2*dot
    #pragma unroll
    for (int m = 0; m < 4; ++m) {
        const float4 sj = *reinterpret_cast<const float4*>(&S32[base + (m << 8) + (lane << 2)]);
        #pragma unroll
        for (int ii = 0; ii < 4; ++ii) {
            d32[ii][m * 4 + 0] = (si[ii] + sj.x) - 2.f * d32[ii][m * 4 + 0];
            d32[ii][m * 4 + 1] = (si[ii] + sj.y) - 2.f * d32[ii][m * 4 + 1];
            d32[ii][m * 4 + 2] = (si[ii] + sj.z) - 2.f * d32[ii][m * 4 + 2];
            d32[ii][m * 4 + 3] = (si[ii] + sj.w) - 2.f * d32[ii][m * 4 + 3];
        }
    }

    const unsigned long long below = (1ull << lane) - 1;
    #pragma unroll
    for (int ii = 0; ii < 4; ++ii) {
        int i = i0 + wv * 4 + ii;
        // ---- threshold: bisection with ballot-count (no shfl chains)
        float lo = -1.f, hi = 2.f * (si[ii] + smax) + 1.f;
        for (int it = 0; it < 32; ++it) {
            float piv = 0.5f * (lo + hi);
            int cnt = 0;
            #pragma unroll
            for (int r = 0; r < 16; ++r)
                cnt += __popcll(__ballot(d32[ii][r] <= piv));
            if (cnt >= KNN) { hi = piv; if (cnt <= 56) break; }
            else lo = piv;
        }
        // eps: 4x safety over fp32 distance error bound (F+2)*2^-24*(si+sj)
        float T = hi + 1.6e-5f * (si[ii] + smax);

        // ---- compact via ballot + prefix popcount (no LDS atomics)
        int total = 0;
        #pragma unroll
        for (int r = 0; r < 16; ++r) {
            bool pred = d32[ii][r] <= T;
            unsigned long long mask = __ballot(pred);
            if (pred) {
                int slot = total + __popcll(mask & below);
                if (slot < 64)
                    surv[wv][ii][slot] = ((r >> 2) << 8) + (lane << 2) + (r & 3);
            }
            total += __popcll(mask);
        }
        if (total > 64) {                    // ~never: defer to fb_k
            if (lane == 0) ovf_list[atomicAdd(ovf_cnt, 1)] = i;
            continue;
        }
        __builtin_amdgcn_wave_barrier();
        asm volatile("s_waitcnt lgkmcnt(0)" ::: "memory");

        // ---- exact f64 rescore (one survivor per lane)
        double d64 = DBL_MAX;
        int jabs = 0x7fffffff;
        if (lane < total) {
            int jl = surv[wv][ii][lane];
            jabs = base + jl;
            const float* xj = X + (size_t)jabs * ldx;
            double dot = 0.0;
            #pragma unroll
            for (int f = 0; f < F; ++f)
                dot = fma((double)xis[wv * 4 + ii][f], (double)xj[f], dot);
            d64 = (S64[i] + S64[jabs]) - 2.0 * dot;
        }
        // ---- bitonic sort 64 lanes by (d64, idx) ascending
        #pragma unroll
        for (int k = 2; k <= 64; k <<= 1) {
            #pragma unroll
            for (int s = k >> 1; s > 0; s >>= 1) {
                double od = __shfl_xor(d64, s);
                int oj = __shfl_xor(jabs, s);
                bool otherSmaller = (od < d64) || (od == d64 && oj < jabs);
                bool keepSmaller = (((lane & k) == 0) == ((lane & s) == 0));
                if (otherSmaller == keepSmaller) { d64 = od; jabs = oj; }
            }
        }
        if (lane < KNN) IDX[(size_t)i * KNN + lane] = jabs;
        __builtin_amdgcn_wave_barrier();
    }
}

// ---------------------------------------------------------------------------
// fb_k: exact f64 full scan + 30x min-extract for overflow points only.
// Fixed grid (graph-safe); normally zero work. Register pressure isolated here.
// ---------------------------------------------------------------------------
template<int F>
__global__ __launch_bounds__(256) void fb_k(const float* __restrict__ X, int ldx,
                                            const float* __restrict__ XT,
                                            const double* __restrict__ S64,
                                            int* __restrict__ IDX,
                                            const int* __restrict__ ovf_cnt,
                                            const int* __restrict__ ovf_list) {
    int wv = threadIdx.x >> 6, lane = threadIdx.x & 63;
    int novf = *ovf_cnt;
    __shared__ double xis[4][F];
    for (int t = blockIdx.x * 4 + wv; t < novf; t += 64 * 4) {
        int i = ovf_list[t];
        int base = i & ~(PTS - 1);
        if (lane < F) xis[wv][lane] = (double)X[(size_t)i * ldx + lane];
        __builtin_amdgcn_wave_barrier();
        asm volatile("s_waitcnt lgkmcnt(0)" ::: "memory");
        double dd[16];
        #pragma unroll
        for (int m = 0; m < 4; ++m) {
            int j0 = (m << 8) + (lane << 2);
            double d0 = 0.0, d1 = 0.0, d2 = 0.0, d3 = 0.0;
            #pragma unroll
            for (int f = 0; f < F; ++f) {
                double xif = xis[wv][f];
                const float4 xj = *reinterpret_cast<const float4*>(&XT[(size_t)f * NPTS + base + j0]);
                d0 = fma(xif, (double)xj.x, d0);
                d1 = fma(xif, (double)xj.y, d1);
                d2 = fma(xif, (double)xj.z, d2);
                d3 = fma(xif, (double)xj.w, d3);
            }
            dd[m * 4 + 0] = (S64[i] + S64[base + j0 + 0]) - 2.0 * d0;
            dd[m * 4 + 1] = (S64[i] + S64[base + j0 + 1]) - 2.0 * d1;
            dd[m * 4 + 2] = (S64[i] + S64[base + j0 + 2]) - 2.0 * d2;
            dd[m * 4 + 3] = (S64[i] + S64[base + j0 + 3]) - 2.0 * d3;
        }
        for (int k = 0; k < KNN; ++k) {
            double bd = DBL_MAX;
            int bj = 0x7fffffff;
            #pragma unroll
            for (int r = 0; r < 16; ++r) {
                int j = ((r >> 2) << 8) + (lane << 2) + (r & 3);
                if (dd[r] < bd) { bd = dd[r]; bj = j; }
            }
            #pragma unroll
            for (int off = 32; off; off >>= 1) {
                double od = __shfl_xor(bd, off);
                int oj = __shfl_xor(bj, off);
                if (od < bd || (od == bd && oj < bj)) { bd = od; bj = oj; }
            }
            if (((bj >> 2) & 63) == lane) {
                int r = ((bj >> 8) << 2) | (bj & 3);
                #pragma unroll
                for (int rr = 0; rr < 16; ++rr) if (rr == r) dd[rr] = DBL_MAX;
            }
            if (lane == 0) IDX[(size_t)i * KNN + k] = base + bj;
        }
        __builtin_amdgcn_wave_barrier();
    }
}

// ---------------------------------------------------------------------------
// mg: per-point layer-1 decomposition: h1_edge = relu(m_i + g_j)
// ---------------------------------------------------------------------------
template<int F>
__global__ __launch_bounds__(256) void mg_k(const float* __restrict__ X, int ldx,
                                            const float* __restrict__ W1,
                                            const float* __restrict__ B1,
                                            float* __restrict__ Mo, float* __restrict__ Go) {
    int tid = blockIdx.x * 256 + threadIdx.x;
    int pp = tid >> 6, c = tid & 63;
    float m = B1[c], g = 0.f;
    #pragma unroll
    for (int f = 0; f < F; ++f) {
        float xv = X[(size_t)pp * ldx + f];
        float wt = W1[f * DIM + c];
        float wb = W1[(F + f) * DIM + c];
        m = fmaf(xv, wt - wb, m);
        g = fmaf(xv, wb, g);
    }
    Mo[(size_t)pp * DIM + c] = m;
    Go[(size_t)pp * DIM + c] = g;
}

// ---------------------------------------------------------------------------
// edge: per point (1 wave each): h2 = relu(b2 + relu(m_i+g_j) @ W2), max over j.
// ---------------------------------------------------------------------------
__global__ __launch_bounds__(256) void edge_k(const int* __restrict__ IDX,
                                              const float* __restrict__ G,
                                              const float* __restrict__ Mb,
                                              const float* __restrict__ W2,
                                              const float* __restrict__ B2,
                                              float* __restrict__ OUT, int ldo) {
    int wv = threadIdx.x >> 6, lane = threadIdx.x & 63;
    int i = blockIdx.x * 4 + wv;
    __shared__ __align__(16) float h1[4][DIM];
    float w2c[DIM];
    #pragma unroll
    for (int k2 = 0; k2 < DIM; ++k2) w2c[k2] = W2[k2 * DIM + lane];
    float mi = Mb[(size_t)i * DIM + lane];
    float b2c = B2[lane];
    float acc = -FLT_MAX;
    for (int nb = 0; nb < KNN; ++nb) {
        int j = IDX[(size_t)i * KNN + nb];
        float h = fmaxf(mi + G[(size_t)j * DIM + lane], 0.f);
        h1[wv][lane] = h;
        __builtin_amdgcn_wave_barrier();
        asm volatile("s_waitcnt lgkmcnt(0)" ::: "memory");
        float h2 = b2c;
        #pragma unroll
        for (int k2 = 0; k2 < DIM; k2 += 4) {
            const float4 hv = *reinterpret_cast<const float4*>(&h1[wv][k2]);
            h2 = fmaf(hv.x, w2c[k2 + 0], h2);
            h2 = fmaf(hv.y, w2c[k2 + 1], h2);
            h2 = fmaf(hv.z, w2c[k2 + 2], h2);
            h2 = fmaf(hv.w, w2c[k2 + 3], h2);
        }
        acc = fmaxf(acc, fmaxf(h2, 0.f));
        __builtin_amdgcn_wave_barrier();
    }
    OUT[(size_t)i * ldo + lane] = acc;
}

// ---------------------------------------------------------------------------
// fp32 tiled GEMM: C[M x N] = act(A[M x Kd] @ W[Kd x N] + bias)
// TM x TN block tile, 256 threads as 16x16, (TM/16)x(TN/16) microtile.
// ---------------------------------------------------------------------------
template<int TM, int TN, int BK, bool RELU>
__global__ __launch_bounds__(256) void gemm_k(const float* __restrict__ A, int Kd,
                                              const float* __restrict__ W, int N,
                                              const float* __restrict__ Bias,
                                              float* __restrict__ C) {
    constexpr int MM = TM / 16, MN = TN / 16;
    __shared__ __align__(16) float As_t[BK][TM + 4];
    __shared__ __align__(16) float Ws[BK][TN];
    int bm = blockIdx.y * TM, bn = blockIdx.x * TN;
    int tid = threadIdx.x;
    int tr = tid >> 4, tc = tid & 15;
    float acc[MM][MN] = {};
    for (int k0 = 0; k0 < Kd; k0 += BK) {
        #pragma unroll
        for (int l = tid; l < TM * (BK / 4); l += 256) {
            int r = l / (BK / 4), q = l & (BK / 4 - 1);
            const float4 a4 = *reinterpret_cast<const float4*>(&A[(size_t)(bm + r) * Kd + k0 + 4 * q]);
            As_t[4 * q + 0][r] = a4.x;
            As_t[4 * q + 1][r] = a4.y;
            As_t[4 * q + 2][r] = a4.z;
            As_t[4 * q + 3][r] = a4.w;
        }
        #pragma unroll
        for (int l = tid; l < BK * (TN / 4); l += 256) {
            int r = l / (TN / 4), q = l & (TN / 4 - 1);
            *reinterpret_cast<float4*>(&Ws[r][4 * q]) =
                *reinterpret_cast<const float4*>(&W[(size_t)(k0 + r) * N + bn + 4 * q]);
        }
        __syncthreads();
        #pragma unroll
        for (int kk = 0; kk < BK; ++kk) {
            float a[MM], w[MN];
            #pragma unroll
            for (int u = 0; u < MM; u += 4) {
                const float4 v4 = *reinterpret_cast<const float4*>(&As_t[kk][tr * MM + u]);
                a[u] = v4.x; a[u + 1] = v4.y; a[u + 2] = v4.z; a[u + 3] = v4.w;
            }
            #pragma unroll
            for (int v = 0; v < MN; v += 4) {
                const float4 v4 = *reinterpret_cast<const float4*>(&Ws[kk][tc * MN + v]);
                w[v] = v4.x; w[v + 1] = v4.y; w[v + 2] = v4.z; w[v + 3] = v4.w;
            }
            #pragma unroll
            for (int u = 0; u < MM; ++u)
                #pragma unroll
                for (int v = 0; v < MN; ++v)
                    acc[u][v] = fmaf(a[u], w[v], acc[u][v]);
        }
        __syncthreads();
    }
    #pragma unroll
    for (int u = 0; u < MM; ++u) {
        int row = bm + tr * MM + u;
        #pragma unroll
        for (int v = 0; v < MN; v += 4) {
            int col = bn + tc * MN + v;
            float4 o;
            o.x = acc[u][v + 0] + Bias[col + 0];
            o.y = acc[u][v + 1] + Bias[col + 1];
            o.z = acc[u][v + 2] + Bias[col + 2];
            o.w = acc[u][v + 3] + Bias[col + 3];
            if (RELU) {
                o.x = fmaxf(o.x, 0.f); o.y = fmaxf(o.y, 0.f);
                o.z = fmaxf(o.z, 0.f); o.w = fmaxf(o.w, 0.f);
            }
            *reinterpret_cast<float4*>(&C[(size_t)row * N + col]) = o;
        }
    }
}

// ---------------------------------------------------------------------------
template<int F>
static void run_conv(const float* Xin, int ldx,
                     const float* W1, const float* B1,
                     const float* W2, const float* B2,
                     float* OUT, int ldo,
                     float* XT, float* S32, double* S64, float* SMAX,
                     float* Mb, float* Gb, int* IDX,
                     int* ovf_cnt, int* ovf_list,
                     hipStream_t stream) {
    prep_k<F><<<NPTS / 256, 256, 0, stream>>>(Xin, ldx, S32, S64, XT);
    smax_k<<<NG, 256, 0, stream>>>(S32, SMAX, ovf_cnt);
    knn_k<F><<<NPTS / 16, 256, 0, stream>>>(Xin, ldx, XT, S32, S64, SMAX, IDX,
                                            ovf_cnt, ovf_list);
    fb_k<F><<<64, 256, 0, stream>>>(Xin, ldx, XT, S64, IDX, ovf_cnt, ovf_list);
    mg_k<F><<<NPTS * DIM / 256, 256, 0, stream>>>(Xin, ldx, W1, B1, Mb, Gb);
    edge_k<<<NPTS / 4, 256, 0, stream>>>(IDX, Gb, Mb, W2, B2, OUT, ldo);
}

extern "C" void kernel_launch(void* const* d_in, const int* in_sizes, int n_in,
                              void* d_out, int out_size, void* d_ws, size_t ws_size,
                              hipStream_t stream) {
    (void)in_sizes; (void)n_in; (void)out_size; (void)ws_size;
    const float* x    = (const float*)d_in[0];
    const float* c1w1 = (const float*)d_in[2];  const float* c1b1 = (const float*)d_in[3];
    const float* c1w2 = (const float*)d_in[4];  const float* c1b2 = (const float*)d_in[5];
    const float* c2w1 = (const float*)d_in[6];  const float* c2b1 = (const float*)d_in[7];
    const float* c2w2 = (const float*)d_in[8];  const float* c2b2 = (const float*)d_in[9];
    const float* c3w1 = (const float*)d_in[10]; const float* c3b1 = (const float*)d_in[11];
    const float* c3w2 = (const float*)d_in[12]; const float* c3b2 = (const float*)d_in[13];
    const float* lw   = (const float*)d_in[14]; const float* lb   = (const float*)d_in[15];
    const float* hw1  = (const float*)d_in[16]; const float* hb1  = (const float*)d_in[17];
    const float* hw2  = (const float*)d_in[18]; const float* hb2  = (const float*)d_in[19];
    const float* hw3  = (const float*)d_in[20]; const float* hb3  = (const float*)d_in[21];
    float* out = (float*)d_out;

    // workspace layout: XC | IDX | OVF | union(conv scratch, head scratch)
    float* XC  = (float*)d_ws;                        // NPTS*192
    int*   IDX = (int*)(XC + (size_t)NPTS * 192);     // NPTS*30
    int*   ovf_cnt  = IDX + (size_t)NPTS * KNN;       // 1
    int*   ovf_list = ovf_cnt + 1;                    // NPTS
    float* SCR = (float*)(ovf_list + NPTS + 1);       // even offset -> 8B aligned
    // conv-phase view of SCR
    float*  XT   = SCR;                                   // 64*NPTS floats
    double* S64  = (double*)(XT + (size_t)64 * NPTS);     // NPTS doubles
    float*  S32  = (float*)(S64 + NPTS);                  // NPTS floats
    float*  SMAX = S32 + NPTS;                            // 64 floats (32 used)
    float*  Mb   = SMAX + 64;                             // NPTS*64
    float*  Gb   = Mb + (size_t)NPTS * DIM;               // NPTS*64
    // head-phase view of SCR
    float* H1 = SCR;                        // CHUNK*1024
    float* H2 = H1 + (size_t)CHUNK * 1024;  // CHUNK*256
    float* H3 = H2 + (size_t)CHUNK * 256;   // CHUNK*128

    run_conv<14>(x,        14,  c1w1, c1b1, c1w2, c1b2, XC + 0,   192,
                 XT, S32, S64, SMAX, Mb, Gb, IDX, ovf_cnt, ovf_list, stream);
    run_conv<64>(XC + 0,   192, c2w1, c2b1, c2w2, c2b2, XC + 64,  192,
                 XT, S32, S64, SMAX, Mb, Gb, IDX, ovf_cnt, ovf_list, stream);
    run_conv<64>(XC + 64,  192, c3w1, c3b1, c3w2, c3b2, XC + 128, 192,
                 XT, S32, S64, SMAX, Mb, Gb, IDX, ovf_cnt, ovf_list, stream);

    for (int ch = 0; ch < 4; ++ch) {
        const float* a0 = XC + (size_t)ch * CHUNK * 192;
        float* o0 = out + (size_t)ch * CHUNK * 64;
        gemm_k<128, 128, 16, true ><<<dim3(1024 / 128, CHUNK / 128), 256, 0, stream>>>(a0, 192,  lw,  1024, lb,  H1);
        gemm_k< 64, 128, 16, true ><<<dim3(256  / 128, CHUNK / 64 ), 256, 0, stream>>>(H1, 1024, hw1, 256,  hb1, H2);
        gemm_k< 64, 128, 16, true ><<<dim3(128  / 128, CHUNK / 64 ), 256, 0, stream>>>(H2, 256,  hw2, 128,  hb2, H3);
        gemm_k< 64,  64, 16, false><<<dim3(64   / 64 , CHUNK / 64 ), 256, 0, stream>>>(H3, 128,  hw3, 64,   hb3, o0);
    }
}

// Round 6
// 1616.461 us; speedup vs baseline: 2.6002x; 1.1901x over previous
//
#include <hip/hip_runtime.h>
#include <hip/hip_bf16.h>
#include <float.h>

#define NG    32
#define PTS   1024
#define NPTS  (NG*PTS)      // 32768
#define KNN   30
#define DIM   64
#define CHUNK 8192

typedef __attribute__((ext_vector_type(8))) short bf16x8;
typedef __attribute__((ext_vector_type(4))) float f32x4;
typedef unsigned short ushort_t;

// ---------------------------------------------------------------------------
// prep: per-point sum of squares (f32 + f64) + transpose XT[f][p]
// ---------------------------------------------------------------------------
template<int F>
__global__ __launch_bounds__(256) void prep_k(const float* __restrict__ X, int ldx,
                                              float* __restrict__ S32,
                                              double* __restrict__ S64,
                                              float* __restrict__ XT) {
    int p = blockIdx.x * 256 + threadIdx.x;
    float s32 = 0.f;
    double s64 = 0.0;
    #pragma unroll
    for (int f = 0; f < F; ++f) {
        float v = X[(size_t)p * ldx + f];
        s32 = fmaf(v, v, s32);
        s64 = fma((double)v, (double)v, s64);
        XT[(size_t)f * NPTS + p] = v;
    }
    S32[p] = s32;
    S64[p] = s64;
}

// per-graph max of S32 (for the prune-margin eps) + zero the overflow counter
__global__ __launch_bounds__(256) void smax_k(const float* __restrict__ S32,
                                              float* __restrict__ SMAX,
                                              int* __restrict__ ovf_cnt) {
    if (blockIdx.x == 0 && threadIdx.x == 0) *ovf_cnt = 0;
    int g = blockIdx.x;
    int lane = threadIdx.x & 63, wv = threadIdx.x >> 6;
    float m = 0.f;
    for (int t = threadIdx.x; t < PTS; t += 256) m = fmaxf(m, S32[(size_t)g * PTS + t]);
    #pragma unroll
    for (int off = 32; off; off >>= 1) m = fmaxf(m, __shfl_xor(m, off));
    __shared__ float wm[4];
    if (lane == 0) wm[wv] = m;
    __syncthreads();
    if (threadIdx.x == 0)
        SMAX[g] = fmaxf(fmaxf(wm[0], wm[1]), fmaxf(wm[2], wm[3]));
}

// ---------------------------------------------------------------------------
// knn: block = 16 points, each wave owns 4 points (4x data reuse per load).
// fp32 distances -> ballot-bisection threshold -> ballot-prefix compact ->
// exact f64 rescore of <=64 survivors -> in-wave bitonic -> top-30.
// Overflow (>64 survivors, ~never) deferred to fb_k.
// ---------------------------------------------------------------------------
template<int F>
__global__ __launch_bounds__(256) void knn_k(const float* __restrict__ X, int ldx,
                                             const float* __restrict__ XT,
                                             const float* __restrict__ S32,
                                             const double* __restrict__ S64,
                                             const float* __restrict__ SMAX,
                                             int* __restrict__ IDX,
                                             int* __restrict__ ovf_cnt,
                                             int* __restrict__ ovf_list) {
    constexpr int FP = (F + 3) & ~3;          // padded row for float4 LDS reads
    int wv = threadIdx.x >> 6;
    int lane = threadIdx.x & 63;
    int i0 = blockIdx.x * 16;                 // 16 points per block, one graph
    int base = i0 & ~(PTS - 1);
    __shared__ __align__(16) float xis[16][FP];
    __shared__ int surv[4][4][64];
    for (int l = threadIdx.x; l < 16 * F; l += 256) {
        int pt = l / F, f = l - pt * F;
        xis[pt][f] = X[(size_t)(i0 + pt) * ldx + f];
    }
    __syncthreads();

    float si[4];
    #pragma unroll
    for (int ii = 0; ii < 4; ++ii) si[ii] = S32[i0 + wv * 4 + ii];
    float smax = SMAX[i0 >> 10];

    // ---- phase A: fp32 dot products, 16 j per lane x 4 i per wave
    float d32[4][16];
    #pragma unroll
    for (int ii = 0; ii < 4; ++ii)
        #pragma unroll
        for (int r = 0; r < 16; ++r) d32[ii][r] = 0.f;

    constexpr int F4 = F & ~3;
    for (int f4 = 0; f4 < F4; f4 += 4) {
        float4 xi[4];
        #pragma unroll
        for (int ii = 0; ii < 4; ++ii)
            xi[ii] = *reinterpret_cast<const float4*>(&xis[wv * 4 + ii][f4]);
        #pragma unroll
        for (int fo = 0; fo < 4; ++fo) {
            int f = f4 + fo;
            #pragma unroll
            for (int m = 0; m < 4; ++m) {
                const float4 xj = *reinterpret_cast<const float4*>(
                    &XT[(size_t)f * NPTS + base + (m << 8) + (lane << 2)]);
                #pragma unroll
                for (int ii = 0; ii < 4; ++ii) {
                    float xif = (fo == 0) ? xi[ii].x : (fo == 1) ? xi[ii].y
                               : (fo == 2) ? xi[ii].z : xi[ii].w;
                    d32[ii][m * 4 + 0] = fmaf(xif, xj.x, d32[ii][m * 4 + 0]);
                    d32[ii][m * 4 + 1] = fmaf(xif, xj.y, d32[ii][m * 4 + 1]);
                    d32[ii][m * 4 + 2] = fmaf(xif, xj.z, d32[ii][m * 4 + 2]);
                    d32[ii][m * 4 + 3] = fmaf(xif, xj.w, d32[ii][m * 4 + 3]);
                }
            }
        }
    }
    for (int f = F4; f < F; ++f) {          // tail (F=14)
        float xif[4];
        #pragma unroll
        for (int ii = 0; ii < 4; ++ii) xif[ii] = xis[wv * 4 + ii][f];
        #pragma unroll
        for (int m = 0; m < 4; ++m) {
            const float4 xj = *reinterpret_cast<const float4*>(
                &XT[(size_t)f * NPTS + base + (m << 8) + (lane << 2)]);
            #pragma unroll
            for (int ii = 0; ii < 4; ++ii) {
                d32[ii][m * 4 + 0] = fmaf(xif[ii], xj.x, d32[ii][m * 4 + 0]);
                d32[ii][m * 4 + 1] = fmaf(xif[ii], xj.y, d32[ii][m * 4 + 1]);
                d32[ii][m * 4 + 2] = fmaf(xif[ii], xj.z, d32[ii][m * 4 + 2]);
                d32[ii][m * 4 + 3] = fmaf(xif[ii], xj.w, d32[ii][m * 4 + 3]);
            }
        }
    }
    // finalize d = si + sj - 2*dot
    #pragma unroll
    for (int m = 0; m < 4; ++m) {
        const float4 sj = *reinterpret_cast<const float4*>(&S32[base + (m << 8) + (lane << 2)]);
        #pragma unroll
        for (int ii = 0; ii < 4; ++ii) {
            d32[ii][m * 4 + 0] = (si[ii] + sj.x) - 2.f * d32[ii][m * 4 + 0];
            d32[ii][m * 4 + 1] = (si[ii] + sj.y) - 2.f * d32[ii][m * 4 + 1];
            d32[ii][m * 4 + 2] = (si[ii] + sj.z) - 2.f * d32[ii][m * 4 + 2];
            d32[ii][m * 4 + 3] = (si[ii] + sj.w) - 2.f * d32[ii][m * 4 + 3];
        }
    }

    const unsigned long long below = (1ull << lane) - 1;
    #pragma unroll
    for (int ii = 0; ii < 4; ++ii) {
        int i = i0 + wv * 4 + ii;
        // ---- threshold: bisection with ballot-count
        float lo = -1.f, hi = 2.f * (si[ii] + smax) + 1.f;
        for (int it = 0; it < 32; ++it) {
            float piv = 0.5f * (lo + hi);
            int cnt = 0;
            #pragma unroll
            for (int r = 0; r < 16; ++r)
                cnt += __popcll(__ballot(d32[ii][r] <= piv));
            if (cnt >= KNN) { hi = piv; if (cnt <= 56) break; }
            else lo = piv;
        }
        // eps: 4x safety over fp32 distance error bound (F+2)*2^-24*(si+sj)
        float T = hi + 1.6e-5f * (si[ii] + smax);

        // ---- compact via ballot + prefix popcount (no LDS atomics)
        int total = 0;
        #pragma unroll
        for (int r = 0; r < 16; ++r) {
            bool pred = d32[ii][r] <= T;
            unsigned long long mask = __ballot(pred);
            if (pred) {
                int slot = total + __popcll(mask & below);
                if (slot < 64)
                    surv[wv][ii][slot] = ((r >> 2) << 8) + (lane << 2) + (r & 3);
            }
            total += __popcll(mask);
        }
        if (total > 64) {                    // ~never: defer to fb_k
            if (lane == 0) ovf_list[atomicAdd(ovf_cnt, 1)] = i;
            continue;
        }
        __builtin_amdgcn_wave_barrier();
        asm volatile("s_waitcnt lgkmcnt(0)" ::: "memory");

        // ---- exact f64 rescore (one survivor per lane)
        double d64 = DBL_MAX;
        int jabs = 0x7fffffff;
        if (lane < total) {
            int jl = surv[wv][ii][lane];
            jabs = base + jl;
            const float* xj = X + (size_t)jabs * ldx;
            double dot = 0.0;
            #pragma unroll
            for (int f = 0; f < F; ++f)
                dot = fma((double)xis[wv * 4 + ii][f], (double)xj[f], dot);
            d64 = (S64[i] + S64[jabs]) - 2.0 * dot;
        }
        // ---- bitonic sort 64 lanes by (d64, idx) ascending
        #pragma unroll
        for (int k = 2; k <= 64; k <<= 1) {
            #pragma unroll
            for (int s = k >> 1; s > 0; s >>= 1) {
                double od = __shfl_xor(d64, s);
                int oj = __shfl_xor(jabs, s);
                bool otherSmaller = (od < d64) || (od == d64 && oj < jabs);
                bool keepSmaller = (((lane & k) == 0) == ((lane & s) == 0));
                if (otherSmaller == keepSmaller) { d64 = od; jabs = oj; }
            }
        }
        if (lane < KNN) IDX[(size_t)i * KNN + lane] = jabs;
        __builtin_amdgcn_wave_barrier();
    }
}

// ---------------------------------------------------------------------------
// fb_k: exact f64 full scan + 30x min-extract for overflow points only.
// ---------------------------------------------------------------------------
template<int F>
__global__ __launch_bounds__(256) void fb_k(const float* __restrict__ X, int ldx,
                                            const float* __restrict__ XT,
                                            const double* __restrict__ S64,
                                            int* __restrict__ IDX,
                                            const int* __restrict__ ovf_cnt,
                                            const int* __restrict__ ovf_list) {
    int wv = threadIdx.x >> 6, lane = threadIdx.x & 63;
    int novf = *ovf_cnt;
    __shared__ double xis[4][F];
    for (int t = blockIdx.x * 4 + wv; t < novf; t += 64 * 4) {
        int i = ovf_list[t];
        int base = i & ~(PTS - 1);
        if (lane < F) xis[wv][lane] = (double)X[(size_t)i * ldx + lane];
        __builtin_amdgcn_wave_barrier();
        asm volatile("s_waitcnt lgkmcnt(0)" ::: "memory");
        double dd[16];
        #pragma unroll
        for (int m = 0; m < 4; ++m) {
            int j0 = (m << 8) + (lane << 2);
            double d0 = 0.0, d1 = 0.0, d2 = 0.0, d3 = 0.0;
            #pragma unroll
            for (int f = 0; f < F; ++f) {
                double xif = xis[wv][f];
                const float4 xj = *reinterpret_cast<const float4*>(&XT[(size_t)f * NPTS + base + j0]);
                d0 = fma(xif, (double)xj.x, d0);
                d1 = fma(xif, (double)xj.y, d1);
                d2 = fma(xif, (double)xj.z, d2);
                d3 = fma(xif, (double)xj.w, d3);
            }
            dd[m * 4 + 0] = (S64[i] + S64[base + j0 + 0]) - 2.0 * d0;
            dd[m * 4 + 1] = (S64[i] + S64[base + j0 + 1]) - 2.0 * d1;
            dd[m * 4 + 2] = (S64[i] + S64[base + j0 + 2]) - 2.0 * d2;
            dd[m * 4 + 3] = (S64[i] + S64[base + j0 + 3]) - 2.0 * d3;
        }
        for (int k = 0; k < KNN; ++k) {
            double bd = DBL_MAX;
            int bj = 0x7fffffff;
            #pragma unroll
            for (int r = 0; r < 16; ++r) {
                int j = ((r >> 2) << 8) + (lane << 2) + (r & 3);
                if (dd[r] < bd) { bd = dd[r]; bj = j; }
            }
            #pragma unroll
            for (int off = 32; off; off >>= 1) {
                double od = __shfl_xor(bd, off);
                int oj = __shfl_xor(bj, off);
                if (od < bd || (od == bd && oj < bj)) { bd = od; bj = oj; }
            }
            if (((bj >> 2) & 63) == lane) {
                int r = ((bj >> 8) << 2) | (bj & 3);
                #pragma unroll
                for (int rr = 0; rr < 16; ++rr) if (rr == r) dd[rr] = DBL_MAX;
            }
            if (lane == 0) IDX[(size_t)i * KNN + k] = base + bj;
        }
        __builtin_amdgcn_wave_barrier();
    }
}

// ---------------------------------------------------------------------------
// mg: per-point layer-1 decomposition: h1_edge = relu(m_i + g_j)
// ---------------------------------------------------------------------------
template<int F>
__global__ __launch_bounds__(256) void mg_k(const float* __restrict__ X, int ldx,
                                            const float* __restrict__ W1,
                                            const float* __restrict__ B1,
                                            float* __restrict__ Mo, float* __restrict__ Go) {
    int tid = blockIdx.x * 256 + threadIdx.x;
    int pp = tid >> 6, c = tid & 63;
    float m = B1[c], g = 0.f;
    #pragma unroll
    for (int f = 0; f < F; ++f) {
        float xv = X[(size_t)pp * ldx + f];
        float wt = W1[f * DIM + c];
        float wb = W1[(F + f) * DIM + c];
        m = fmaf(xv, wt - wb, m);
        g = fmaf(xv, wb, g);
    }
    Mo[(size_t)pp * DIM + c] = m;
    Go[(size_t)pp * DIM + c] = g;
}

// ---------------------------------------------------------------------------
// edge (MFMA): per wave = 1 point. Build 30 h1 rows in LDS (all gathers issued
// up-front -> latency amortized), bf16 hi/lo split, then h1[32x64] @ W2[64x64]
// on the matrix pipe (3 products: hiHi + hiLo + loHi; error ~2^-18 rel).
// Max-pool in C-fragment layout (row=(lane>>4)*4+reg, col=lane&15), pad rows
// 30/31 masked. out = relu(max + b2).
// ---------------------------------------------------------------------------
__global__ __launch_bounds__(256) void edge_k(const int* __restrict__ IDX,
                                              const float* __restrict__ G,
                                              const float* __restrict__ Mb,
                                              const float* __restrict__ W2,
                                              const float* __restrict__ B2,
                                              float* __restrict__ OUT, int ldo) {
    __shared__ ushort_t w2hi[64][72], w2lo[64][72];       // W2^T [c][k], 2x9216B
    __shared__ ushort_t h1hi[4][32][72], h1lo[4][32][72]; // per wave [nb][k]
    int wv = threadIdx.x >> 6, lane = threadIdx.x & 63;
    int i = blockIdx.x * 4 + wv;
    int col16 = lane & 15, grp = lane >> 4, grp8 = (lane >> 4) << 3;

    // stage W2^T hi/lo (bf16 RNE split)
    for (int l = threadIdx.x; l < 4096; l += 256) {
        int c = l & 63, k = l >> 6;
        float w = W2[k * 64 + c];
        __hip_bfloat16 bh = __float2bfloat16(w);
        __hip_bfloat16 bl = __float2bfloat16(w - __bfloat162float(bh));
        w2hi[c][k] = *reinterpret_cast<ushort_t*>(&bh);
        w2lo[c][k] = *reinterpret_cast<ushort_t*>(&bl);
    }
    __syncthreads();

    float mi = Mb[(size_t)i * DIM + lane];
    const int* idxrow = IDX + (size_t)i * KNN;
    int idxv = (lane < KNN) ? idxrow[lane] : 0;
    float g[KNN];
    #pragma unroll
    for (int nb = 0; nb < KNN; ++nb) {            // independent gathers, deep ILP
        int j = __shfl(idxv, nb);
        g[nb] = G[(size_t)j * DIM + lane];
    }
    #pragma unroll
    for (int nb = 0; nb < KNN; ++nb) {
        float h = fmaxf(mi + g[nb], 0.f);
        __hip_bfloat16 bh = __float2bfloat16(h);
        __hip_bfloat16 bl = __float2bfloat16(h - __bfloat162float(bh));
        h1hi[wv][nb][lane] = *reinterpret_cast<ushort_t*>(&bh);
        h1lo[wv][nb][lane] = *reinterpret_cast<ushort_t*>(&bl);
    }
    h1hi[wv][30][lane] = 0; h1lo[wv][30][lane] = 0;   // pad rows
    h1hi[wv][31][lane] = 0; h1lo[wv][31][lane] = 0;
    __builtin_amdgcn_wave_barrier();
    asm volatile("s_waitcnt lgkmcnt(0)" ::: "memory");

    // A fragments: row = lane&15 (+16*m), k = (lane>>4)*8 + j (+32*ks)
    bf16x8 ahi[2][2], alo[2][2];
    #pragma unroll
    for (int m = 0; m < 2; ++m)
        #pragma unroll
        for (int ks = 0; ks < 2; ++ks) {
            ahi[m][ks] = *reinterpret_cast<const bf16x8*>(&h1hi[wv][m * 16 + col16][ks * 32 + grp8]);
            alo[m][ks] = *reinterpret_cast<const bf16x8*>(&h1lo[wv][m * 16 + col16][ks * 32 + grp8]);
        }

    float myout = 0.f;
    #pragma unroll
    for (int n = 0; n < 4; ++n) {
        bf16x8 bhi[2], blo[2];
        #pragma unroll
        for (int ks = 0; ks < 2; ++ks) {
            bhi[ks] = *reinterpret_cast<const bf16x8*>(&w2hi[n * 16 + col16][ks * 32 + grp8]);
            blo[ks] = *reinterpret_cast<const bf16x8*>(&w2lo[n * 16 + col16][ks * 32 + grp8]);
        }
        f32x4 acc0 = {0.f, 0.f, 0.f, 0.f}, acc1 = {0.f, 0.f, 0.f, 0.f};
        #pragma unroll
        for (int ks = 0; ks < 2; ++ks) {
            acc0 = __builtin_amdgcn_mfma_f32_16x16x32_bf16(ahi[0][ks], bhi[ks], acc0, 0, 0, 0);
            acc1 = __builtin_amdgcn_mfma_f32_16x16x32_bf16(ahi[1][ks], bhi[ks], acc1, 0, 0, 0);
            acc0 = __builtin_amdgcn_mfma_f32_16x16x32_bf16(ahi[0][ks], blo[ks], acc0, 0, 0, 0);
            acc1 = __builtin_amdgcn_mfma_f32_16x16x32_bf16(ahi[1][ks], blo[ks], acc1, 0, 0, 0);
            acc0 = __builtin_amdgcn_mfma_f32_16x16x32_bf16(alo[0][ks], bhi[ks], acc0, 0, 0, 0);
            acc1 = __builtin_amdgcn_mfma_f32_16x16x32_bf16(alo[1][ks], bhi[ks], acc1, 0, 0, 0);
        }
        // max over rows (m=0: rows 0-15 all valid; m=1: rows 16+grp*4+reg, valid<30)
        float cm = fmaxf(fmaxf(acc0[0], acc0[1]), fmaxf(acc0[2], acc0[3]));
        cm = fmaxf(cm, fmaxf(acc1[0], acc1[1]));
        if (grp < 3) cm = fmaxf(cm, fmaxf(acc1[2], acc1[3]));
        cm = fmaxf(cm, __shfl_xor(cm, 16));
        cm = fmaxf(cm, __shfl_xor(cm, 32));
        if (grp == n) myout = cm;                 // col = n*16 + (lane&15) = lane
    }
    OUT[(size_t)i * ldo + lane] = fmaxf(myout + B2[lane], 0.f);
}

// ---------------------------------------------------------------------------
// fp32 tiled GEMM: C[M x N] = act(A[M x Kd] @ W[Kd x N] + bias)
// ---------------------------------------------------------------------------
template<int TM, int TN, int BK, bool RELU>
__global__ __launch_bounds__(256) void gemm_k(const float* __restrict__ A, int Kd,
                                              const float* __restrict__ W, int N,
                                              const float* __restrict__ Bias,
                                              float* __restrict__ C) {
    constexpr int MM = TM / 16, MN = TN / 16;
    __shared__ __align__(16) float As_t[BK][TM + 4];
    __shared__ __align__(16) float Ws[BK][TN];
    int bm = blockIdx.y * TM, bn = blockIdx.x * TN;
    int tid = threadIdx.x;
    int tr = tid >> 4, tc = tid & 15;
    float acc[MM][MN] = {};
    for (int k0 = 0; k0 < Kd; k0 += BK) {
        #pragma unroll
        for (int l = tid; l < TM * (BK / 4); l += 256) {
            int r = l / (BK / 4), q = l & (BK / 4 - 1);
            const float4 a4 = *reinterpret_cast<const float4*>(&A[(size_t)(bm + r) * Kd + k0 + 4 * q]);
            As_t[4 * q + 0][r] = a4.x;
            As_t[4 * q + 1][r] = a4.y;
            As_t[4 * q + 2][r] = a4.z;
            As_t[4 * q + 3][r] = a4.w;
        }
        #pragma unroll
        for (int l = tid; l < BK * (TN / 4); l += 256) {
            int r = l / (TN / 4), q = l & (TN / 4 - 1);
            *reinterpret_cast<float4*>(&Ws[r][4 * q]) =
                *reinterpret_cast<const float4*>(&W[(size_t)(k0 + r) * N + bn + 4 * q]);
        }
        __syncthreads();
        #pragma unroll
        for (int kk = 0; kk < BK; ++kk) {
            float a[MM], w[MN];
            #pragma unroll
            for (int u = 0; u < MM; u += 4) {
                const float4 v4 = *reinterpret_cast<const float4*>(&As_t[kk][tr * MM + u]);
                a[u] = v4.x; a[u + 1] = v4.y; a[u + 2] = v4.z; a[u + 3] = v4.w;
            }
            #pragma unroll
            for (int v = 0; v < MN; v += 4) {
                const float4 v4 = *reinterpret_cast<const float4*>(&Ws[kk][tc * MN + v]);
                w[v] = v4.x; w[v + 1] = v4.y; w[v + 2] = v4.z; w[v + 3] = v4.w;
            }
            #pragma unroll
            for (int u = 0; u < MM; ++u)
                #pragma unroll
                for (int v = 0; v < MN; ++v)
                    acc[u][v] = fmaf(a[u], w[v], acc[u][v]);
        }
        __syncthreads();
    }
    #pragma unroll
    for (int u = 0; u < MM; ++u) {
        int row = bm + tr * MM + u;
        #pragma unroll
        for (int v = 0; v < MN; v += 4) {
            int col = bn + tc * MN + v;
            float4 o;
            o.x = acc[u][v + 0] + Bias[col + 0];
            o.y = acc[u][v + 1] + Bias[col + 1];
            o.z = acc[u][v + 2] + Bias[col + 2];
            o.w = acc[u][v + 3] + Bias[col + 3];
            if (RELU) {
                o.x = fmaxf(o.x, 0.f); o.y = fmaxf(o.y, 0.f);
                o.z = fmaxf(o.z, 0.f); o.w = fmaxf(o.w, 0.f);
            }
            *reinterpret_cast<float4*>(&C[(size_t)row * N + col]) = o;
        }
    }
}

// ---------------------------------------------------------------------------
template<int F>
static void run_conv(const float* Xin, int ldx,
                     const float* W1, const float* B1,
                     const float* W2, const float* B2,
                     float* OUT, int ldo,
                     float* XT, float* S32, double* S64, float* SMAX,
                     float* Mb, float* Gb, int* IDX,
                     int* ovf_cnt, int* ovf_list,
                     hipStream_t stream) {
    prep_k<F><<<NPTS / 256, 256, 0, stream>>>(Xin, ldx, S32, S64, XT);
    smax_k<<<NG, 256, 0, stream>>>(S32, SMAX, ovf_cnt);
    knn_k<F><<<NPTS / 16, 256, 0, stream>>>(Xin, ldx, XT, S32, S64, SMAX, IDX,
                                            ovf_cnt, ovf_list);
    fb_k<F><<<64, 256, 0, stream>>>(Xin, ldx, XT, S64, IDX, ovf_cnt, ovf_list);
    mg_k<F><<<NPTS * DIM / 256, 256, 0, stream>>>(Xin, ldx, W1, B1, Mb, Gb);
    edge_k<<<NPTS / 4, 256, 0, stream>>>(IDX, Gb, Mb, W2, B2, OUT, ldo);
}

extern "C" void kernel_launch(void* const* d_in, const int* in_sizes, int n_in,
                              void* d_out, int out_size, void* d_ws, size_t ws_size,
                              hipStream_t stream) {
    (void)in_sizes; (void)n_in; (void)out_size; (void)ws_size;
    const float* x    = (const float*)d_in[0];
    const float* c1w1 = (const float*)d_in[2];  const float* c1b1 = (const float*)d_in[3];
    const float* c1w2 = (const float*)d_in[4];  const float* c1b2 = (const float*)d_in[5];
    const float* c2w1 = (const float*)d_in[6];  const float* c2b1 = (const float*)d_in[7];
    const float* c2w2 = (const float*)d_in[8];  const float* c2b2 = (const float*)d_in[9];
    const float* c3w1 = (const float*)d_in[10]; const float* c3b1 = (const float*)d_in[11];
    const float* c3w2 = (const float*)d_in[12]; const float* c3b2 = (const float*)d_in[13];
    const float* lw   = (const float*)d_in[14]; const float* lb   = (const float*)d_in[15];
    const float* hw1  = (const float*)d_in[16]; const float* hb1  = (const float*)d_in[17];
    const float* hw2  = (const float*)d_in[18]; const float* hb2  = (const float*)d_in[19];
    const float* hw3  = (const float*)d_in[20]; const float* hb3  = (const float*)d_in[21];
    float* out = (float*)d_out;

    // workspace layout: XC | IDX | OVF | union(conv scratch, head scratch)
    float* XC  = (float*)d_ws;                        // NPTS*192
    int*   IDX = (int*)(XC + (size_t)NPTS * 192);     // NPTS*30
    int*   ovf_cnt  = IDX + (size_t)NPTS * KNN;       // 1
    int*   ovf_list = ovf_cnt + 1;                    // NPTS
    float* SCR = (float*)(ovf_list + NPTS + 1);       // even offset -> 8B aligned
    // conv-phase view of SCR
    float*  XT   = SCR;                                   // 64*NPTS floats
    double* S64  = (double*)(XT + (size_t)64 * NPTS);     // NPTS doubles
    float*  S32  = (float*)(S64 + NPTS);                  // NPTS floats
    float*  SMAX = S32 + NPTS;                            // 64 floats (32 used)
    float*  Mb   = SMAX + 64;                             // NPTS*64
    float*  Gb   = Mb + (size_t)NPTS * DIM;               // NPTS*64
    // head-phase view of SCR
    float* H1 = SCR;                        // CHUNK*1024
    float* H2 = H1 + (size_t)CHUNK * 1024;  // CHUNK*256
    float* H3 = H2 + (size_t)CHUNK * 256;   // CHUNK*128

    run_conv<14>(x,        14,  c1w1, c1b1, c1w2, c1b2, XC + 0,   192,
                 XT, S32, S64, SMAX, Mb, Gb, IDX, ovf_cnt, ovf_list, stream);
    run_conv<64>(XC + 0,   192, c2w1, c2b1, c2w2, c2b2, XC + 64,  192,
                 XT, S32, S64, SMAX, Mb, Gb, IDX, ovf_cnt, ovf_list, stream);
    run_conv<64>(XC + 64,  192, c3w1, c3b1, c3w2, c3b2, XC + 128, 192,
                 XT, S32, S64, SMAX, Mb, Gb, IDX, ovf_cnt, ovf_list, stream);

    for (int ch = 0; ch < 4; ++ch) {
        const float* a0 = XC + (size_t)ch * CHUNK * 192;
        float* o0 = out + (size_t)ch * CHUNK * 64;
        gemm_k<128, 128, 16, true ><<<dim3(1024 / 128, CHUNK / 128), 256, 0, stream>>>(a0, 192,  lw,  1024, lb,  H1);
        gemm_k< 64, 128, 16, true ><<<dim3(256  / 128, CHUNK / 64 ), 256, 0, stream>>>(H1, 1024, hw1, 256,  hb1, H2);
        gemm_k< 64, 128, 16, true ><<<dim3(128  / 128, CHUNK / 64 ), 256, 0, stream>>>(H2, 256,  hw2, 128,  hb2, H3);
        gemm_k< 64,  64, 16, false><<<dim3(64   / 64 , CHUNK / 64 ), 256, 0, stream>>>(H3, 128,  hw3, 64,   hb3, o0);
    }
}

// Round 7
// 1397.159 us; speedup vs baseline: 3.0083x; 1.1570x over previous
//
#include <hip/hip_runtime.h>
#include <hip/hip_bf16.h>
#include <float.h>

#define NG    32
#define PTS   1024
#define NPTS  (NG*PTS)      // 32768
#define KNN   30
#define DIM   64
#define CHUNK 8192

typedef __attribute__((ext_vector_type(8))) short bf16x8;
typedef __attribute__((ext_vector_type(4))) float f32x4;
typedef unsigned short ushort_t;

__device__ inline void bfsplit(float v, ushort_t& h, ushort_t& l) {
    __hip_bfloat16 bh = __float2bfloat16(v);
    float r = v - __bfloat162float(bh);
    __hip_bfloat16 bl = __float2bfloat16(r);
    h = *reinterpret_cast<ushort_t*>(&bh);
    l = *reinterpret_cast<ushort_t*>(&bl);
}

// ---------------------------------------------------------------------------
// prep: per-point sum of squares (f32 + f64) + transpose XT[f][p]
// ---------------------------------------------------------------------------
template<int F>
__global__ __launch_bounds__(256) void prep_k(const float* __restrict__ X, int ldx,
                                              float* __restrict__ S32,
                                              double* __restrict__ S64,
                                              float* __restrict__ XT) {
    int p = blockIdx.x * 256 + threadIdx.x;
    float s32 = 0.f;
    double s64 = 0.0;
    #pragma unroll
    for (int f = 0; f < F; ++f) {
        float v = X[(size_t)p * ldx + f];
        s32 = fmaf(v, v, s32);
        s64 = fma((double)v, (double)v, s64);
        XT[(size_t)f * NPTS + p] = v;
    }
    S32[p] = s32;
    S64[p] = s64;
}

// per-graph max of S32 (for the prune-margin eps) + zero the overflow counter
__global__ __launch_bounds__(256) void smax_k(const float* __restrict__ S32,
                                              float* __restrict__ SMAX,
                                              int* __restrict__ ovf_cnt) {
    if (blockIdx.x == 0 && threadIdx.x == 0) *ovf_cnt = 0;
    int g = blockIdx.x;
    int lane = threadIdx.x & 63, wv = threadIdx.x >> 6;
    float m = 0.f;
    for (int t = threadIdx.x; t < PTS; t += 256) m = fmaxf(m, S32[(size_t)g * PTS + t]);
    #pragma unroll
    for (int off = 32; off; off >>= 1) m = fmaxf(m, __shfl_xor(m, off));
    __shared__ float wm[4];
    if (lane == 0) wm[wv] = m;
    __syncthreads();
    if (threadIdx.x == 0)
        SMAX[g] = fmaxf(fmaxf(wm[0], wm[1]), fmaxf(wm[2], wm[3]));
}

// ---------------------------------------------------------------------------
// knn: block = 16 points, each wave owns 4 points (4x data reuse per load).
// fp32 distances -> ballot-bisection threshold -> ballot-prefix compact ->
// exact f64 rescore of <=64 survivors -> in-wave bitonic -> top-30.
// ---------------------------------------------------------------------------
template<int F>
__global__ __launch_bounds__(256) void knn_k(const float* __restrict__ X, int ldx,
                                             const float* __restrict__ XT,
                                             const float* __restrict__ S32,
                                             const double* __restrict__ S64,
                                             const float* __restrict__ SMAX,
                                             int* __restrict__ IDX,
                                             int* __restrict__ ovf_cnt,
                                             int* __restrict__ ovf_list) {
    constexpr int FP = (F + 3) & ~3;
    int wv = threadIdx.x >> 6;
    int lane = threadIdx.x & 63;
    int i0 = blockIdx.x * 16;
    int base = i0 & ~(PTS - 1);
    __shared__ __align__(16) float xis[16][FP];
    __shared__ int surv[4][4][64];
    for (int l = threadIdx.x; l < 16 * F; l += 256) {
        int pt = l / F, f = l - pt * F;
        xis[pt][f] = X[(size_t)(i0 + pt) * ldx + f];
    }
    __syncthreads();

    float si[4];
    #pragma unroll
    for (int ii = 0; ii < 4; ++ii) si[ii] = S32[i0 + wv * 4 + ii];
    float smax = SMAX[i0 >> 10];

    float d32[4][16];
    #pragma unroll
    for (int ii = 0; ii < 4; ++ii)
        #pragma unroll
        for (int r = 0; r < 16; ++r) d32[ii][r] = 0.f;

    constexpr int F4 = F & ~3;
    for (int f4 = 0; f4 < F4; f4 += 4) {
        float4 xi[4];
        #pragma unroll
        for (int ii = 0; ii < 4; ++ii)
            xi[ii] = *reinterpret_cast<const float4*>(&xis[wv * 4 + ii][f4]);
        #pragma unroll
        for (int fo = 0; fo < 4; ++fo) {
            int f = f4 + fo;
            #pragma unroll
            for (int m = 0; m < 4; ++m) {
                const float4 xj = *reinterpret_cast<const float4*>(
                    &XT[(size_t)f * NPTS + base + (m << 8) + (lane << 2)]);
                #pragma unroll
                for (int ii = 0; ii < 4; ++ii) {
                    float xif = (fo == 0) ? xi[ii].x : (fo == 1) ? xi[ii].y
                               : (fo == 2) ? xi[ii].z : xi[ii].w;
                    d32[ii][m * 4 + 0] = fmaf(xif, xj.x, d32[ii][m * 4 + 0]);
                    d32[ii][m * 4 + 1] = fmaf(xif, xj.y, d32[ii][m * 4 + 1]);
                    d32[ii][m * 4 + 2] = fmaf(xif, xj.z, d32[ii][m * 4 + 2]);
                    d32[ii][m * 4 + 3] = fmaf(xif, xj.w, d32[ii][m * 4 + 3]);
                }
            }
        }
    }
    for (int f = F4; f < F; ++f) {
        float xif[4];
        #pragma unroll
        for (int ii = 0; ii < 4; ++ii) xif[ii] = xis[wv * 4 + ii][f];
        #pragma unroll
        for (int m = 0; m < 4; ++m) {
            const float4 xj = *reinterpret_cast<const float4*>(
                &XT[(size_t)f * NPTS + base + (m << 8) + (lane << 2)]);
            #pragma unroll
            for (int ii = 0; ii < 4; ++ii) {
                d32[ii][m * 4 + 0] = fmaf(xif[ii], xj.x, d32[ii][m * 4 + 0]);
                d32[ii][m * 4 + 1] = fmaf(xif[ii], xj.y, d32[ii][m * 4 + 1]);
                d32[ii][m * 4 + 2] = fmaf(xif[ii], xj.z, d32[ii][m * 4 + 2]);
                d32[ii][m * 4 + 3] = fmaf(xif[ii], xj.w, d32[ii][m * 4 + 3]);
            }
        }
    }
    #pragma unroll
    for (int m = 0; m < 4; ++m) {
        const float4 sj = *reinterpret_cast<const float4*>(&S32[base + (m << 8) + (lane << 2)]);
        #pragma unroll
        for (int ii = 0; ii < 4; ++ii) {
            d32[ii][m * 4 + 0] = (si[ii] + sj.x) - 2.f * d32[ii][m * 4 + 0];
            d32[ii][m * 4 + 1] = (si[ii] + sj.y) - 2.f * d32[ii][m * 4 + 1];
            d32[ii][m * 4 + 2] = (si[ii] + sj.z) - 2.f * d32[ii][m * 4 + 2];
            d32[ii][m * 4 + 3] = (si[ii] + sj.w) - 2.f * d32[ii][m * 4 + 3];
        }
    }

    const unsigned long long below = (1ull << lane) - 1;
    #pragma unroll
    for (int ii = 0; ii < 4; ++ii) {
        int i = i0 + wv * 4 + ii;
        float lo = -1.f, hi = 2.f * (si[ii] + smax) + 1.f;
        for (int it = 0; it < 32; ++it) {
            float piv = 0.5f * (lo + hi);
            int cnt = 0;
            #pragma unroll
            for (int r = 0; r < 16; ++r)
                cnt += __popcll(__ballot(d32[ii][r] <= piv));
            if (cnt >= KNN) { hi = piv; if (cnt <= 56) break; }
            else lo = piv;
        }
        float T = hi + 1.6e-5f * (si[ii] + smax);

        int total = 0;
        #pragma unroll
        for (int r = 0; r < 16; ++r) {
            bool pred = d32[ii][r] <= T;
            unsigned long long mask = __ballot(pred);
            if (pred) {
                int slot = total + __popcll(mask & below);
                if (slot < 64)
                    surv[wv][ii][slot] = ((r >> 2) << 8) + (lane << 2) + (r & 3);
            }
            total += __popcll(mask);
        }
        if (total > 64) {
            if (lane == 0) ovf_list[atomicAdd(ovf_cnt, 1)] = i;
            continue;
        }
        __builtin_amdgcn_wave_barrier();
        asm volatile("s_waitcnt lgkmcnt(0)" ::: "memory");

        double d64 = DBL_MAX;
        int jabs = 0x7fffffff;
        if (lane < total) {
            int jl = surv[wv][ii][lane];
            jabs = base + jl;
            const float* xj = X + (size_t)jabs * ldx;
            double dot = 0.0;
            #pragma unroll
            for (int f = 0; f < F; ++f)
                dot = fma((double)xis[wv * 4 + ii][f], (double)xj[f], dot);
            d64 = (S64[i] + S64[jabs]) - 2.0 * dot;
        }
        #pragma unroll
        for (int k = 2; k <= 64; k <<= 1) {
            #pragma unroll
            for (int s = k >> 1; s > 0; s >>= 1) {
                double od = __shfl_xor(d64, s);
                int oj = __shfl_xor(jabs, s);
                bool otherSmaller = (od < d64) || (od == d64 && oj < jabs);
                bool keepSmaller = (((lane & k) == 0) == ((lane & s) == 0));
                if (otherSmaller == keepSmaller) { d64 = od; jabs = oj; }
            }
        }
        if (lane < KNN) IDX[(size_t)i * KNN + lane] = jabs;
        __builtin_amdgcn_wave_barrier();
    }
}

// ---------------------------------------------------------------------------
// fb_k: exact f64 full scan + 30x min-extract for overflow points only.
// ---------------------------------------------------------------------------
template<int F>
__global__ __launch_bounds__(256) void fb_k(const float* __restrict__ X, int ldx,
                                            const float* __restrict__ XT,
                                            const double* __restrict__ S64,
                                            int* __restrict__ IDX,
                                            const int* __restrict__ ovf_cnt,
                                            const int* __restrict__ ovf_list) {
    int wv = threadIdx.x >> 6, lane = threadIdx.x & 63;
    int novf = *ovf_cnt;
    __shared__ double xis[4][F];
    for (int t = blockIdx.x * 4 + wv; t < novf; t += 64 * 4) {
        int i = ovf_list[t];
        int base = i & ~(PTS - 1);
        if (lane < F) xis[wv][lane] = (double)X[(size_t)i * ldx + lane];
        __builtin_amdgcn_wave_barrier();
        asm volatile("s_waitcnt lgkmcnt(0)" ::: "memory");
        double dd[16];
        #pragma unroll
        for (int m = 0; m < 4; ++m) {
            int j0 = (m << 8) + (lane << 2);
            double d0 = 0.0, d1 = 0.0, d2 = 0.0, d3 = 0.0;
            #pragma unroll
            for (int f = 0; f < F; ++f) {
                double xif = xis[wv][f];
                const float4 xj = *reinterpret_cast<const float4*>(&XT[(size_t)f * NPTS + base + j0]);
                d0 = fma(xif, (double)xj.x, d0);
                d1 = fma(xif, (double)xj.y, d1);
                d2 = fma(xif, (double)xj.z, d2);
                d3 = fma(xif, (double)xj.w, d3);
            }
            dd[m * 4 + 0] = (S64[i] + S64[base + j0 + 0]) - 2.0 * d0;
            dd[m * 4 + 1] = (S64[i] + S64[base + j0 + 1]) - 2.0 * d1;
            dd[m * 4 + 2] = (S64[i] + S64[base + j0 + 2]) - 2.0 * d2;
            dd[m * 4 + 3] = (S64[i] + S64[base + j0 + 3]) - 2.0 * d3;
        }
        for (int k = 0; k < KNN; ++k) {
            double bd = DBL_MAX;
            int bj = 0x7fffffff;
            #pragma unroll
            for (int r = 0; r < 16; ++r) {
                int j = ((r >> 2) << 8) + (lane << 2) + (r & 3);
                if (dd[r] < bd) { bd = dd[r]; bj = j; }
            }
            #pragma unroll
            for (int off = 32; off; off >>= 1) {
                double od = __shfl_xor(bd, off);
                int oj = __shfl_xor(bj, off);
                if (od < bd || (od == bd && oj < bj)) { bd = od; bj = oj; }
            }
            if (((bj >> 2) & 63) == lane) {
                int r = ((bj >> 8) << 2) | (bj & 3);
                #pragma unroll
                for (int rr = 0; rr < 16; ++rr) if (rr == r) dd[rr] = DBL_MAX;
            }
            if (lane == 0) IDX[(size_t)i * KNN + k] = base + bj;
        }
        __builtin_amdgcn_wave_barrier();
    }
}

// ---------------------------------------------------------------------------
// mg: per-point layer-1 decomposition: h1_edge = relu(m_i + g_j)
// ---------------------------------------------------------------------------
template<int F>
__global__ __launch_bounds__(256) void mg_k(const float* __restrict__ X, int ldx,
                                            const float* __restrict__ W1,
                                            const float* __restrict__ B1,
                                            float* __restrict__ Mo, float* __restrict__ Go) {
    int tid = blockIdx.x * 256 + threadIdx.x;
    int pp = tid >> 6, c = tid & 63;
    float m = B1[c], g = 0.f;
    #pragma unroll
    for (int f = 0; f < F; ++f) {
        float xv = X[(size_t)pp * ldx + f];
        float wt = W1[f * DIM + c];
        float wb = W1[(F + f) * DIM + c];
        m = fmaf(xv, wt - wb, m);
        g = fmaf(xv, wb, g);
    }
    Mo[(size_t)pp * DIM + c] = m;
    Go[(size_t)pp * DIM + c] = g;
}

// ---------------------------------------------------------------------------
// edge (MFMA): per wave = 1 point; h1[32x64] @ W2[64x64], bf16 hi/lo 3-product
// ---------------------------------------------------------------------------
__global__ __launch_bounds__(256) void edge_k(const int* __restrict__ IDX,
                                              const float* __restrict__ G,
                                              const float* __restrict__ Mb,
                                              const float* __restrict__ W2,
                                              const float* __restrict__ B2,
                                              float* __restrict__ OUT, int ldo) {
    __shared__ ushort_t w2hi[64][72], w2lo[64][72];
    __shared__ ushort_t h1hi[4][32][72], h1lo[4][32][72];
    int wv = threadIdx.x >> 6, lane = threadIdx.x & 63;
    int i = blockIdx.x * 4 + wv;
    int col16 = lane & 15, grp = lane >> 4, grp8 = (lane >> 4) << 3;

    for (int l = threadIdx.x; l < 4096; l += 256) {
        int c = l & 63, k = l >> 6;
        bfsplit(W2[k * 64 + c], w2hi[c][k], w2lo[c][k]);
    }
    __syncthreads();

    float mi = Mb[(size_t)i * DIM + lane];
    const int* idxrow = IDX + (size_t)i * KNN;
    int idxv = (lane < KNN) ? idxrow[lane] : 0;
    float g[KNN];
    #pragma unroll
    for (int nb = 0; nb < KNN; ++nb) {
        int j = __shfl(idxv, nb);
        g[nb] = G[(size_t)j * DIM + lane];
    }
    #pragma unroll
    for (int nb = 0; nb < KNN; ++nb) {
        float h = fmaxf(mi + g[nb], 0.f);
        bfsplit(h, h1hi[wv][nb][lane], h1lo[wv][nb][lane]);
    }
    h1hi[wv][30][lane] = 0; h1lo[wv][30][lane] = 0;
    h1hi[wv][31][lane] = 0; h1lo[wv][31][lane] = 0;
    __builtin_amdgcn_wave_barrier();
    asm volatile("s_waitcnt lgkmcnt(0)" ::: "memory");

    bf16x8 ahi[2][2], alo[2][2];
    #pragma unroll
    for (int m = 0; m < 2; ++m)
        #pragma unroll
        for (int ks = 0; ks < 2; ++ks) {
            ahi[m][ks] = *reinterpret_cast<const bf16x8*>(&h1hi[wv][m * 16 + col16][ks * 32 + grp8]);
            alo[m][ks] = *reinterpret_cast<const bf16x8*>(&h1lo[wv][m * 16 + col16][ks * 32 + grp8]);
        }

    float myout = 0.f;
    #pragma unroll
    for (int n = 0; n < 4; ++n) {
        bf16x8 bhi[2], blo[2];
        #pragma unroll
        for (int ks = 0; ks < 2; ++ks) {
            bhi[ks] = *reinterpret_cast<const bf16x8*>(&w2hi[n * 16 + col16][ks * 32 + grp8]);
            blo[ks] = *reinterpret_cast<const bf16x8*>(&w2lo[n * 16 + col16][ks * 32 + grp8]);
        }
        f32x4 acc0 = {0.f, 0.f, 0.f, 0.f}, acc1 = {0.f, 0.f, 0.f, 0.f};
        #pragma unroll
        for (int ks = 0; ks < 2; ++ks) {
            acc0 = __builtin_amdgcn_mfma_f32_16x16x32_bf16(ahi[0][ks], bhi[ks], acc0, 0, 0, 0);
            acc1 = __builtin_amdgcn_mfma_f32_16x16x32_bf16(ahi[1][ks], bhi[ks], acc1, 0, 0, 0);
            acc0 = __builtin_amdgcn_mfma_f32_16x16x32_bf16(ahi[0][ks], blo[ks], acc0, 0, 0, 0);
            acc1 = __builtin_amdgcn_mfma_f32_16x16x32_bf16(ahi[1][ks], blo[ks], acc1, 0, 0, 0);
            acc0 = __builtin_amdgcn_mfma_f32_16x16x32_bf16(alo[0][ks], bhi[ks], acc0, 0, 0, 0);
            acc1 = __builtin_amdgcn_mfma_f32_16x16x32_bf16(alo[1][ks], bhi[ks], acc1, 0, 0, 0);
        }
        float cm = fmaxf(fmaxf(acc0[0], acc0[1]), fmaxf(acc0[2], acc0[3]));
        cm = fmaxf(cm, fmaxf(acc1[0], acc1[1]));
        if (grp < 3) cm = fmaxf(cm, fmaxf(acc1[2], acc1[3]));
        cm = fmaxf(cm, __shfl_xor(cm, 16));
        cm = fmaxf(cm, __shfl_xor(cm, 32));
        if (grp == n) myout = cm;
    }
    OUT[(size_t)i * ldo + lane] = fmaxf(myout + B2[lane], 0.f);
}

// ---------------------------------------------------------------------------
// wcvt: one-time W[K][N] -> W^T hi/lo bf16 [N][K]
// ---------------------------------------------------------------------------
__global__ __launch_bounds__(256) void wcvt_k(const float* __restrict__ W, int K, int N,
                                              ushort_t* __restrict__ Th,
                                              ushort_t* __restrict__ Tl) {
    int idx = blockIdx.x * 256 + threadIdx.x;
    if (idx >= K * N) return;
    int k = idx / N, n = idx - k * N;
    ushort_t h, l;
    bfsplit(W[idx], h, l);
    Th[(size_t)n * K + k] = h;
    Tl[(size_t)n * K + k] = l;
}

// ---------------------------------------------------------------------------
// gemmx: MFMA GEMM, 128x128 tile, BK=32, bf16 hi/lo 3-product.
// A: fp32 (convert-on-stage) or bf16-pair; W: pre-transposed bf16-pair [N][K].
// Output: fp32 or bf16-pair; bias+optional relu fused.
// ---------------------------------------------------------------------------
template<bool A32, bool OUT16, bool RELU>
__global__ __launch_bounds__(256) void gemmx_k(
    const float* __restrict__ Afp,
    const ushort_t* __restrict__ Agh, const ushort_t* __restrict__ Agl, int Kd,
    const ushort_t* __restrict__ Bth, const ushort_t* __restrict__ Btl,
    int N, const float* __restrict__ Bias,
    float* __restrict__ Cfp, ushort_t* __restrict__ Cgh, ushort_t* __restrict__ Cgl) {
    constexpr int BM = 128, BN = 128, BKP = 40;
    __shared__ ushort_t Ah[BM][BKP], Al[BM][BKP], Bh[BN][BKP], Bl[BN][BKP];
    int tid = threadIdx.x;
    int lane = tid & 63, wv = tid >> 6;
    int wr = wv >> 1, wc = wv & 1;
    int col16 = lane & 15, grp = lane >> 4, grp8 = grp << 3;
    int bm = blockIdx.y * BM, bn = blockIdx.x * BN;
    f32x4 acc[4][4];
    #pragma unroll
    for (int mf = 0; mf < 4; ++mf)
        #pragma unroll
        for (int nf = 0; nf < 4; ++nf) acc[mf][nf] = (f32x4){0.f, 0.f, 0.f, 0.f};

    for (int k0 = 0; k0 < Kd; k0 += 32) {
        if constexpr (A32) {
            for (int l = tid; l < BM * 8; l += 256) {
                int r = l >> 3, c4 = (l & 7) << 2;
                const float4 a = *reinterpret_cast<const float4*>(&Afp[(size_t)(bm + r) * Kd + k0 + c4]);
                ushort4 h4, l4;
                bfsplit(a.x, h4.x, l4.x);
                bfsplit(a.y, h4.y, l4.y);
                bfsplit(a.z, h4.z, l4.z);
                bfsplit(a.w, h4.w, l4.w);
                *reinterpret_cast<ushort4*>(&Ah[r][c4]) = h4;
                *reinterpret_cast<ushort4*>(&Al[r][c4]) = l4;
            }
        } else {
            for (int l = tid; l < BM * 4; l += 256) {
                int r = l >> 2, q = (l & 3) << 3;
                *reinterpret_cast<uint4*>(&Ah[r][q]) =
                    *reinterpret_cast<const uint4*>(&Agh[(size_t)(bm + r) * Kd + k0 + q]);
                *reinterpret_cast<uint4*>(&Al[r][q]) =
                    *reinterpret_cast<const uint4*>(&Agl[(size_t)(bm + r) * Kd + k0 + q]);
            }
        }
        for (int l = tid; l < BN * 4; l += 256) {
            int n = l >> 2, q = (l & 3) << 3;
            *reinterpret_cast<uint4*>(&Bh[n][q]) =
                *reinterpret_cast<const uint4*>(&Bth[(size_t)(bn + n) * Kd + k0 + q]);
            *reinterpret_cast<uint4*>(&Bl[n][q]) =
                *reinterpret_cast<const uint4*>(&Btl[(size_t)(bn + n) * Kd + k0 + q]);
        }
        __syncthreads();

        bf16x8 afh[4], afl[4], bfh[4], bfl[4];
        #pragma unroll
        for (int mf = 0; mf < 4; ++mf) {
            afh[mf] = *reinterpret_cast<const bf16x8*>(&Ah[wr * 64 + mf * 16 + col16][grp8]);
            afl[mf] = *reinterpret_cast<const bf16x8*>(&Al[wr * 64 + mf * 16 + col16][grp8]);
        }
        #pragma unroll
        for (int nf = 0; nf < 4; ++nf) {
            bfh[nf] = *reinterpret_cast<const bf16x8*>(&Bh[wc * 64 + nf * 16 + col16][grp8]);
            bfl[nf] = *reinterpret_cast<const bf16x8*>(&Bl[wc * 64 + nf * 16 + col16][grp8]);
        }
        #pragma unroll
        for (int mf = 0; mf < 4; ++mf)
            #pragma unroll
            for (int nf = 0; nf < 4; ++nf) {
                acc[mf][nf] = __builtin_amdgcn_mfma_f32_16x16x32_bf16(afh[mf], bfh[nf], acc[mf][nf], 0, 0, 0);
                acc[mf][nf] = __builtin_amdgcn_mfma_f32_16x16x32_bf16(afh[mf], bfl[nf], acc[mf][nf], 0, 0, 0);
                acc[mf][nf] = __builtin_amdgcn_mfma_f32_16x16x32_bf16(afl[mf], bfh[nf], acc[mf][nf], 0, 0, 0);
            }
        __syncthreads();
    }

    #pragma unroll
    for (int nf = 0; nf < 4; ++nf) {
        int col = bn + wc * 64 + nf * 16 + col16;
        float b = Bias[col];
        #pragma unroll
        for (int mf = 0; mf < 4; ++mf) {
            #pragma unroll
            for (int rg = 0; rg < 4; ++rg) {
                int row = bm + wr * 64 + mf * 16 + grp * 4 + rg;
                float v = acc[mf][nf][rg] + b;
                if (RELU) v = fmaxf(v, 0.f);
                if constexpr (OUT16) {
                    bfsplit(v, Cgh[(size_t)row * N + col], Cgl[(size_t)row * N + col]);
                } else {
                    Cfp[(size_t)row * N + col] = v;
                }
            }
        }
    }
}

// ---------------------------------------------------------------------------
// fp32 tiled GEMM (small tail layers)
// ---------------------------------------------------------------------------
template<int TM, int TN, int BK, bool RELU>
__global__ __launch_bounds__(256) void gemm_k(const float* __restrict__ A, int Kd,
                                              const float* __restrict__ W, int N,
                                              const float* __restrict__ Bias,
                                              float* __restrict__ C) {
    constexpr int MM = TM / 16, MN = TN / 16;
    __shared__ __align__(16) float As_t[BK][TM + 4];
    __shared__ __align__(16) float Ws[BK][TN];
    int bm = blockIdx.y * TM, bn = blockIdx.x * TN;
    int tid = threadIdx.x;
    int tr = tid >> 4, tc = tid & 15;
    float acc[MM][MN] = {};
    for (int k0 = 0; k0 < Kd; k0 += BK) {
        #pragma unroll
        for (int l = tid; l < TM * (BK / 4); l += 256) {
            int r = l / (BK / 4), q = l & (BK / 4 - 1);
            const float4 a4 = *reinterpret_cast<const float4*>(&A[(size_t)(bm + r) * Kd + k0 + 4 * q]);
            As_t[4 * q + 0][r] = a4.x;
            As_t[4 * q + 1][r] = a4.y;
            As_t[4 * q + 2][r] = a4.z;
            As_t[4 * q + 3][r] = a4.w;
        }
        #pragma unroll
        for (int l = tid; l < BK * (TN / 4); l += 256) {
            int r = l / (TN / 4), q = l & (TN / 4 - 1);
            *reinterpret_cast<float4*>(&Ws[r][4 * q]) =
                *reinterpret_cast<const float4*>(&W[(size_t)(k0 + r) * N + bn + 4 * q]);
        }
        __syncthreads();
        #pragma unroll
        for (int kk = 0; kk < BK; ++kk) {
            float a[MM], w[MN];
            #pragma unroll
            for (int u = 0; u < MM; u += 4) {
                const float4 v4 = *reinterpret_cast<const float4*>(&As_t[kk][tr * MM + u]);
                a[u] = v4.x; a[u + 1] = v4.y; a[u + 2] = v4.z; a[u + 3] = v4.w;
            }
            #pragma unroll
            for (int v = 0; v < MN; v += 4) {
                const float4 v4 = *reinterpret_cast<const float4*>(&Ws[kk][tc * MN + v]);
                w[v] = v4.x; w[v + 1] = v4.y; w[v + 2] = v4.z; w[v + 3] = v4.w;
            }
            #pragma unroll
            for (int u = 0; u < MM; ++u)
                #pragma unroll
                for (int v = 0; v < MN; ++v)
                    acc[u][v] = fmaf(a[u], w[v], acc[u][v]);
        }
        __syncthreads();
    }
    #pragma unroll
    for (int u = 0; u < MM; ++u) {
        int row = bm + tr * MM + u;
        #pragma unroll
        for (int v = 0; v < MN; v += 4) {
            int col = bn + tc * MN + v;
            float4 o;
            o.x = acc[u][v + 0] + Bias[col + 0];
            o.y = acc[u][v + 1] + Bias[col + 1];
            o.z = acc[u][v + 2] + Bias[col + 2];
            o.w = acc[u][v + 3] + Bias[col + 3];
            if (RELU) {
                o.x = fmaxf(o.x, 0.f); o.y = fmaxf(o.y, 0.f);
                o.z = fmaxf(o.z, 0.f); o.w = fmaxf(o.w, 0.f);
            }
            *reinterpret_cast<float4*>(&C[(size_t)row * N + col]) = o;
        }
    }
}

// ---------------------------------------------------------------------------
template<int F>
static void run_conv(const float* Xin, int ldx,
                     const float* W1, const float* B1,
                     const float* W2, const float* B2,
                     float* OUT, int ldo,
                     float* XT, float* S32, double* S64, float* SMAX,
                     float* Mb, float* Gb, int* IDX,
                     int* ovf_cnt, int* ovf_list,
                     hipStream_t stream) {
    prep_k<F><<<NPTS / 256, 256, 0, stream>>>(Xin, ldx, S32, S64, XT);
    smax_k<<<NG, 256, 0, stream>>>(S32, SMAX, ovf_cnt);
    knn_k<F><<<NPTS / 16, 256, 0, stream>>>(Xin, ldx, XT, S32, S64, SMAX, IDX,
                                            ovf_cnt, ovf_list);
    fb_k<F><<<64, 256, 0, stream>>>(Xin, ldx, XT, S64, IDX, ovf_cnt, ovf_list);
    mg_k<F><<<NPTS * DIM / 256, 256, 0, stream>>>(Xin, ldx, W1, B1, Mb, Gb);
    edge_k<<<NPTS / 4, 256, 0, stream>>>(IDX, Gb, Mb, W2, B2, OUT, ldo);
}

extern "C" void kernel_launch(void* const* d_in, const int* in_sizes, int n_in,
                              void* d_out, int out_size, void* d_ws, size_t ws_size,
                              hipStream_t stream) {
    (void)in_sizes; (void)n_in; (void)out_size; (void)ws_size;
    const float* x    = (const float*)d_in[0];
    const float* c1w1 = (const float*)d_in[2];  const float* c1b1 = (const float*)d_in[3];
    const float* c1w2 = (const float*)d_in[4];  const float* c1b2 = (const float*)d_in[5];
    const float* c2w1 = (const float*)d_in[6];  const float* c2b1 = (const float*)d_in[7];
    const float* c2w2 = (const float*)d_in[8];  const float* c2b2 = (const float*)d_in[9];
    const float* c3w1 = (const float*)d_in[10]; const float* c3b1 = (const float*)d_in[11];
    const float* c3w2 = (const float*)d_in[12]; const float* c3b2 = (const float*)d_in[13];
    const float* lw   = (const float*)d_in[14]; const float* lb   = (const float*)d_in[15];
    const float* hw1  = (const float*)d_in[16]; const float* hb1  = (const float*)d_in[17];
    const float* hw2  = (const float*)d_in[18]; const float* hb2  = (const float*)d_in[19];
    const float* hw3  = (const float*)d_in[20]; const float* hb3  = (const float*)d_in[21];
    float* out = (float*)d_out;

    // workspace layout: XC | IDX | OVF | union(conv scratch, head scratch)
    float* XC  = (float*)d_ws;                        // NPTS*192
    int*   IDX = (int*)(XC + (size_t)NPTS * 192);     // NPTS*30
    int*   ovf_cnt  = IDX + (size_t)NPTS * KNN;       // 1
    int*   ovf_list = ovf_cnt + 1;                    // NPTS
    float* SCR = (float*)(ovf_list + NPTS + 1);       // 8B aligned
    // conv-phase view of SCR
    float*  XT   = SCR;                                   // 64*NPTS floats
    double* S64  = (double*)(XT + (size_t)64 * NPTS);     // NPTS doubles
    float*  S32  = (float*)(S64 + NPTS);                  // NPTS floats
    float*  SMAX = S32 + NPTS;                            // 64 floats
    float*  Mb   = SMAX + 64;                             // NPTS*64
    float*  Gb   = Mb + (size_t)NPTS * DIM;               // NPTS*64
    // head-phase view of SCR
    ushort_t* H1h = (ushort_t*)SCR;                       // CHUNK*1024 bf16
    ushort_t* H1l = H1h + (size_t)CHUNK * 1024;           // CHUNK*1024 bf16
    float* H2 = (float*)(H1l + (size_t)CHUNK * 1024);     // CHUNK*256 fp32
    float* H3 = (float*)H1h;                              // alias: H1 dead when H3 written
    ushort_t* Wlwh = (ushort_t*)(H2 + (size_t)CHUNK * 256);
    ushort_t* Wlwl = Wlwh + 192 * 1024;
    ushort_t* Wh1h = Wlwl + 192 * 1024;
    ushort_t* Wh1l = Wh1h + 1024 * 256;

    run_conv<14>(x,        14,  c1w1, c1b1, c1w2, c1b2, XC + 0,   192,
                 XT, S32, S64, SMAX, Mb, Gb, IDX, ovf_cnt, ovf_list, stream);
    run_conv<64>(XC + 0,   192, c2w1, c2b1, c2w2, c2b2, XC + 64,  192,
                 XT, S32, S64, SMAX, Mb, Gb, IDX, ovf_cnt, ovf_list, stream);
    run_conv<64>(XC + 64,  192, c3w1, c3b1, c3w2, c3b2, XC + 128, 192,
                 XT, S32, S64, SMAX, Mb, Gb, IDX, ovf_cnt, ovf_list, stream);

    // one-time weight transpose+split (after convs: W region overlays conv scratch space)
    wcvt_k<<<(192 * 1024 + 255) / 256, 256, 0, stream>>>(lw,  192,  1024, Wlwh, Wlwl);
    wcvt_k<<<(1024 * 256 + 255) / 256, 256, 0, stream>>>(hw1, 1024, 256,  Wh1h, Wh1l);

    for (int ch = 0; ch < 4; ++ch) {
        const float* a0 = XC + (size_t)ch * CHUNK * 192;
        float* o0 = out + (size_t)ch * CHUNK * 64;
        gemmx_k<true, true, true><<<dim3(1024 / 128, CHUNK / 128), 256, 0, stream>>>(
            a0, nullptr, nullptr, 192, Wlwh, Wlwl, 1024, lb, nullptr, H1h, H1l);
        gemmx_k<false, false, true><<<dim3(256 / 128, CHUNK / 128), 256, 0, stream>>>(
            nullptr, H1h, H1l, 1024, Wh1h, Wh1l, 256, hb1, H2, nullptr, nullptr);
        gemm_k<64, 128, 16, true ><<<dim3(128 / 128, CHUNK / 64), 256, 0, stream>>>(H2, 256, hw2, 128, hb2, H3);
        gemm_k<64, 64, 16, false><<<dim3(64 / 64,   CHUNK / 64), 256, 0, stream>>>(H3, 128, hw3, 64,  hb3, o0);
    }
}